// Round 15
// baseline (1863.851 us; speedup 1.0000x reference)
//
#include <hip/hip_runtime.h>
#include <math.h>

// Problem constants
#define BB 4
#define SS 1024
#define DD 256
#define HH 8
#define HD 32
#define D3 768
#define MLP 1024
#define NTOK (BB * SS)   // 4096
#define NSEG 4           // split-K segments for full attention
#define GRID 512         // persistent grid: 2 blocks/CU co-resident

typedef __attribute__((ext_vector_type(8))) short short8;
typedef __attribute__((ext_vector_type(4))) float f32x4;
typedef unsigned short ushort_t;

__device__ __forceinline__ ushort_t f2bfu(float f) {
    union { float f; unsigned i; } u; u.f = f;
    unsigned r = u.i + 0x7fffu + ((u.i >> 16) & 1u);   // RNE
    return (ushort_t)(r >> 16);
}
__device__ __forceinline__ float bfu2f(ushort_t h) {
    union { unsigned i; float f; } u; u.i = ((unsigned)h) << 16; return u.f;
}

#define W_TOT 2097152
#define WL0   196608   // 768*256 = Win_a layer 0
#define WBLK  (W_TOT / 256)
#define PBLK  (NTOK * DD / 256)
#define LDP 40

// V-epilogue helper: token row + V-column -> VT[b][h][d][s] index
__device__ __forceinline__ size_t vt_index(int row, int col512) {
    int b = row >> 10, s = row & (SS - 1);
    int h = col512 >> 5, d = col512 & (HD - 1);
    return (((size_t)b * HH + h) * HD + d) * SS + s;
}

struct MegaArgs {
    const float *Win_a, *Wout_a, *Win_e, *Wout_e, *W1, *W2;      // fp32 weights
    const float *xin, *scale;
    const float *bin_a, *bout_a, *bin_e, *bout_e, *b1, *b2;
    const float *ln1_g, *ln1_b, *ln2_g, *ln2_b, *lnf_g, *lnf_b;
    float *X, *X2;
    ushort_t *Xb, *Xlb, *X2b, *ATb, *QKVb, *QKVl, *VTh, *HMLb, *Wb, *Wl0;
    float2 *Ml;
    float *Of;
    float *dout;
    unsigned *bar;   // [0]=arrivals (monotonic), [1]=phases completed
};

// ---------------------------------------------------------------------------
// Device-wide barrier: monotonic counters, no reset races. All GRID blocks
// must be co-resident (guaranteed by __launch_bounds__(256,2) at grid 512).
// Bounded spin -> wrong answer instead of hang if that assumption breaks.
__device__ __forceinline__ void gbar(unsigned* bar, int phase) {
    __syncthreads();
    __threadfence();                       // release: drain this block's writes
    if (threadIdx.x == 0) {
        unsigned arr = atomicAdd(&bar[0], 1u);
        if (arr == (unsigned)GRID * (unsigned)(phase + 1) - 1u) {
            atomicAdd(&bar[1], 1u);        // last arrival releases the phase
        } else {
            int iters = 0;
            while (atomicAdd(&bar[1], 0u) <= (unsigned)phase && iters < (1 << 20)) {
                __builtin_amdgcn_s_sleep(8);
                iters++;
            }
        }
    }
    __syncthreads();
    __threadfence();                       // acquire: invalidate stale caches
}

// ---------------------------------------------------------------------------
// Phase: fused prep (weights fp32->bf16 (+lo for Win_a l0), x + pos encode)
__device__ __forceinline__ void dev_prep(int vb, const MegaArgs& A) {
    int t = threadIdx.x;
    if (vb < WBLK) {
        int i = vb * 256 + t;
        const float* s; int off;
        if      (i <  393216) { s = A.Win_a;  off = 0;       }
        else if (i <  524288) { s = A.Wout_a; off = 393216;  }
        else if (i <  917504) { s = A.Win_e;  off = 524288;  }
        else if (i < 1048576) { s = A.Wout_e; off = 917504;  }
        else if (i < 1572864) { s = A.W1;     off = 1048576; }
        else                  { s = A.W2;     off = 1572864; }
        float v = s[i - off];
        ushort_t h = f2bfu(v);
        A.Wb[i] = h;
        if (i < WL0) A.Wl0[i] = f2bfu(v - bfu2f(h));
    } else {
        int i = (vb - WBLK) * 256 + t;
        int s = (i >> 8) & (SS - 1);
        float v = A.xin[i] + (float)s * A.scale[0];
        A.X[i] = v;
        ushort_t h = f2bfu(v);
        A.Xb[i] = h;
        A.Xlb[i] = f2bfu(v - bfu2f(h));
    }
}

// ---------------------------------------------------------------------------
// Phase: MFMA GEMM, 64x128 tile. vth!=null: cols >= 512 -> VT transposed.
__device__ __forceinline__ void dev_gemm(
    int bx, int by, char* sm,
    const ushort_t* __restrict__ Aop, const ushort_t* __restrict__ W,
    const float* __restrict__ bias, const float* __restrict__ resid,
    float* __restrict__ outf, ushort_t* __restrict__ outb,
    ushort_t* __restrict__ vth, int N, int K, int act)
{
    ushort_t* As = (ushort_t*)sm;              // 5120 B
    ushort_t* Bs = (ushort_t*)(sm + 5120);     // 10240 B
    const int t = threadIdx.x;
    const int lane = t & 63, wave = t >> 6;
    const int wr = wave >> 1, wc = wave & 1;
    const int m0 = by * 64, n0 = bx * 128;
    const int sr = t >> 2;
    const int sc = (t & 3) * 8;

    const ushort_t* Ag = Aop + (size_t)(m0 + sr) * K + sc;
    const ushort_t* Wg = W + (size_t)(n0 + sr) * K + sc;

    f32x4 acc[2][4];
    #pragma unroll
    for (int i = 0; i < 2; i++)
        #pragma unroll
        for (int j = 0; j < 4; j++)
            acc[i][j] = (f32x4){0.f, 0.f, 0.f, 0.f};

    const int lm = lane & 15, lk = (lane >> 4) * 8;

    uint4 a0 = *(const uint4*)(Ag);
    uint4 b0 = *(const uint4*)(Wg);
    uint4 b1 = *(const uint4*)(Wg + (size_t)64 * K);

    for (int k0 = 0; k0 < K; k0 += 32) {
        __syncthreads();
        *(uint4*)&As[sr * LDP + sc]        = a0;
        *(uint4*)&Bs[sr * LDP + sc]        = b0;
        *(uint4*)&Bs[(sr + 64) * LDP + sc] = b1;
        __syncthreads();
        if (k0 + 32 < K) {
            a0 = *(const uint4*)(Ag + k0 + 32);
            b0 = *(const uint4*)(Wg + k0 + 32);
            b1 = *(const uint4*)(Wg + (size_t)64 * K + k0 + 32);
        }

        short8 af[2], bf[4];
        #pragma unroll
        for (int i = 0; i < 2; i++)
            af[i] = *(const short8*)&As[(wr * 32 + i * 16 + lm) * LDP + lk];
        #pragma unroll
        for (int j = 0; j < 4; j++)
            bf[j] = *(const short8*)&Bs[(wc * 64 + j * 16 + lm) * LDP + lk];
        #pragma unroll
        for (int i = 0; i < 2; i++)
            #pragma unroll
            for (int j = 0; j < 4; j++)
                acc[i][j] = __builtin_amdgcn_mfma_f32_16x16x32_bf16(
                    af[i], bf[j], acc[i][j], 0, 0, 0);
    }

    const int lq = lane >> 4;
    #pragma unroll
    for (int j = 0; j < 4; j++) {
        int col = n0 + wc * 64 + j * 16 + lm;
        float bv = bias[col];
        #pragma unroll
        for (int i = 0; i < 2; i++) {
            #pragma unroll
            for (int r = 0; r < 4; r++) {
                int row = m0 + wr * 32 + i * 16 + lq * 4 + r;
                float v = acc[i][j][r] + bv;
                if (act) v = 0.5f * v * (1.0f + erff(v * 0.70710678118654752f));
                if (vth && col >= 2 * DD) {
                    vth[vt_index(row, col - 2 * DD)] = f2bfu(v);
                } else {
                    size_t idx = (size_t)row * N + col;
                    if (resid) v += resid[idx];
                    if (outf) outf[idx] = v;
                    if (outb) outb[idx] = f2bfu(v);
                }
            }
        }
    }
    __syncthreads();   // protect LDS before next virtual tile reuses it
}

// ---------------------------------------------------------------------------
// Phase: split (hi/lo) MFMA GEMM for layer-0 QKV. Q,K hi/lo; V -> VT hi.
__device__ __forceinline__ void dev_gemm_split(
    int bx, int by, char* sm,
    const ushort_t* __restrict__ Ah, const ushort_t* __restrict__ Al,
    const ushort_t* __restrict__ Wh, const ushort_t* __restrict__ Wl,
    const float* __restrict__ bias,
    ushort_t* __restrict__ outh, ushort_t* __restrict__ outl,
    ushort_t* __restrict__ vth, int N, int K)
{
    ushort_t* Ash = (ushort_t*)sm;               // 5120
    ushort_t* Asl = (ushort_t*)(sm + 5120);      // 5120
    ushort_t* Bsh = (ushort_t*)(sm + 10240);     // 10240
    ushort_t* Bsl = (ushort_t*)(sm + 20480);     // 10240 -> 30720 total
    const int t = threadIdx.x;
    const int lane = t & 63, wave = t >> 6;
    const int wr = wave >> 1, wc = wave & 1;
    const int m0 = by * 64, n0 = bx * 128;
    const int sr = t >> 2;
    const int sc = (t & 3) * 8;

    const size_t oA = (size_t)(m0 + sr) * K + sc;
    const size_t oW = (size_t)(n0 + sr) * K + sc;

    f32x4 acc[2][4];
    #pragma unroll
    for (int i = 0; i < 2; i++)
        #pragma unroll
        for (int j = 0; j < 4; j++)
            acc[i][j] = (f32x4){0.f, 0.f, 0.f, 0.f};

    const int lm = lane & 15, lk = (lane >> 4) * 8;

    uint4 ah0 = *(const uint4*)(Ah + oA);
    uint4 al0 = *(const uint4*)(Al + oA);
    uint4 bh0 = *(const uint4*)(Wh + oW);
    uint4 bh1 = *(const uint4*)(Wh + oW + (size_t)64 * K);
    uint4 bl0 = *(const uint4*)(Wl + oW);
    uint4 bl1 = *(const uint4*)(Wl + oW + (size_t)64 * K);

    for (int k0 = 0; k0 < K; k0 += 32) {
        __syncthreads();
        *(uint4*)&Ash[sr * LDP + sc]        = ah0;
        *(uint4*)&Asl[sr * LDP + sc]        = al0;
        *(uint4*)&Bsh[sr * LDP + sc]        = bh0;
        *(uint4*)&Bsh[(sr + 64) * LDP + sc] = bh1;
        *(uint4*)&Bsl[sr * LDP + sc]        = bl0;
        *(uint4*)&Bsl[(sr + 64) * LDP + sc] = bl1;
        __syncthreads();
        if (k0 + 32 < K) {
            ah0 = *(const uint4*)(Ah + oA + k0 + 32);
            al0 = *(const uint4*)(Al + oA + k0 + 32);
            bh0 = *(const uint4*)(Wh + oW + k0 + 32);
            bh1 = *(const uint4*)(Wh + oW + (size_t)64 * K + k0 + 32);
            bl0 = *(const uint4*)(Wl + oW + k0 + 32);
            bl1 = *(const uint4*)(Wl + oW + (size_t)64 * K + k0 + 32);
        }

        short8 afh[2], afl[2], bfh[4], bfl[4];
        #pragma unroll
        for (int i = 0; i < 2; i++) {
            afh[i] = *(const short8*)&Ash[(wr * 32 + i * 16 + lm) * LDP + lk];
            afl[i] = *(const short8*)&Asl[(wr * 32 + i * 16 + lm) * LDP + lk];
        }
        #pragma unroll
        for (int j = 0; j < 4; j++) {
            bfh[j] = *(const short8*)&Bsh[(wc * 64 + j * 16 + lm) * LDP + lk];
            bfl[j] = *(const short8*)&Bsl[(wc * 64 + j * 16 + lm) * LDP + lk];
        }
        #pragma unroll
        for (int i = 0; i < 2; i++)
            #pragma unroll
            for (int j = 0; j < 4; j++) {
                acc[i][j] = __builtin_amdgcn_mfma_f32_16x16x32_bf16(
                    afl[i], bfh[j], acc[i][j], 0, 0, 0);
                acc[i][j] = __builtin_amdgcn_mfma_f32_16x16x32_bf16(
                    afh[i], bfl[j], acc[i][j], 0, 0, 0);
                acc[i][j] = __builtin_amdgcn_mfma_f32_16x16x32_bf16(
                    afh[i], bfh[j], acc[i][j], 0, 0, 0);
            }
    }

    const int lq = lane >> 4;
    #pragma unroll
    for (int j = 0; j < 4; j++) {
        int col = n0 + wc * 64 + j * 16 + lm;
        float bv = bias[col];
        #pragma unroll
        for (int i = 0; i < 2; i++) {
            #pragma unroll
            for (int r = 0; r < 4; r++) {
                int row = m0 + wr * 32 + i * 16 + lq * 4 + r;
                float v = acc[i][j][r] + bv;
                ushort_t h = f2bfu(v);
                if (col >= 2 * DD) {
                    vth[vt_index(row, col - 2 * DD)] = h;
                } else {
                    size_t idx = (size_t)row * N + col;
                    outh[idx] = h;
                    outl[idx] = f2bfu(v - bfu2f(h));
                }
            }
        }
    }
    __syncthreads();
}

// ---------------------------------------------------------------------------
// Phase: full-row GEMM (N=256) + resid + LayerNorm. COMBINE: split-K combine
// in A staging. 32x256 tile.
template<bool COMBINE>
__device__ __forceinline__ void dev_gemm_ln(
    int bx, char* sm,
    const ushort_t* __restrict__ Aop,
    const float* __restrict__ Of, const float2* __restrict__ Ml,
    const ushort_t* __restrict__ W, const float* __restrict__ bias,
    const float* __restrict__ resid,
    const float* __restrict__ g, const float* __restrict__ bt,
    float* __restrict__ outf, ushort_t* __restrict__ outb, int K)
{
    ushort_t* As = (ushort_t*)sm;              // 2560 B
    ushort_t* Bs = (ushort_t*)(sm + 2560);     // 20480 -> 23040
    float* rsum  = (float*)(sm + 23040);       // 256 B
    float* rsum2 = (float*)(sm + 23296);       // 256 B -> 23552
    const int t = threadIdx.x;
    const int lane = t & 63, wave = t >> 6;
    const int wr = wave >> 1, wc = wave & 1;
    const int m0 = bx * 32;
    const int sr = t >> 2;
    const int sc = (t & 3) * 8;
    const int arow = t >> 2;
    const int acol = (t & 3) * 8;

    const ushort_t* Wg = W + (size_t)sr * K + sc;

    f32x4 acc[8];
    #pragma unroll
    for (int j = 0; j < 8; j++) acc[j] = (f32x4){0.f, 0.f, 0.f, 0.f};

    const int lm = lane & 15, lk = (lane >> 4) * 8;

    for (int k0 = 0; k0 < K; k0 += 32) {
        ushort_t ab[8];
        const bool aload = (t < 128);
        if (aload) {
            const int token = m0 + arow;
            if (COMBINE) {
                const int h = (k0 + acol) >> 5;
                float2 ml[NSEG];
                float M = -1e30f;
                #pragma unroll
                for (int s = 0; s < NSEG; s++) {
                    ml[s] = Ml[((size_t)s * NTOK + token) * HH + h];
                    M = fmaxf(M, ml[s].x);
                }
                float wgt[NSEG]; float denom = 0.f;
                #pragma unroll
                for (int s = 0; s < NSEG; s++) {
                    wgt[s] = __expf(ml[s].x - M);
                    denom += ml[s].y * wgt[s];
                }
                const float inv = 1.0f / denom;
                float a8[8] = {};
                #pragma unroll
                for (int s = 0; s < NSEG; s++) {
                    const float* p = Of + ((size_t)s * NTOK + token) * DD + k0 + acol;
                    float4 x0 = *(const float4*)p;
                    float4 x1 = *(const float4*)(p + 4);
                    a8[0] += x0.x * wgt[s]; a8[1] += x0.y * wgt[s];
                    a8[2] += x0.z * wgt[s]; a8[3] += x0.w * wgt[s];
                    a8[4] += x1.x * wgt[s]; a8[5] += x1.y * wgt[s];
                    a8[6] += x1.z * wgt[s]; a8[7] += x1.w * wgt[s];
                }
                #pragma unroll
                for (int c = 0; c < 8; c++) ab[c] = f2bfu(a8[c] * inv);
            } else {
                uint4 av = *(const uint4*)(Aop + (size_t)(m0 + arow) * K + k0 + acol);
                *(uint4*)ab = av;
            }
        }
        uint4 b0 = *(const uint4*)(Wg + k0);
        uint4 b1 = *(const uint4*)(Wg + (size_t)64 * K + k0);
        uint4 b2 = *(const uint4*)(Wg + (size_t)128 * K + k0);
        uint4 b3 = *(const uint4*)(Wg + (size_t)192 * K + k0);
        __syncthreads();
        if (aload) *(uint4*)&As[arow * LDP + acol] = *(uint4*)ab;
        *(uint4*)&Bs[sr * LDP + sc]         = b0;
        *(uint4*)&Bs[(sr + 64) * LDP + sc]  = b1;
        *(uint4*)&Bs[(sr + 128) * LDP + sc] = b2;
        *(uint4*)&Bs[(sr + 192) * LDP + sc] = b3;
        __syncthreads();

        short8 af = *(const short8*)&As[(wr * 16 + lm) * LDP + lk];
        #pragma unroll
        for (int j = 0; j < 8; j++) {
            short8 bf = *(const short8*)&Bs[(wc * 128 + j * 16 + lm) * LDP + lk];
            acc[j] = __builtin_amdgcn_mfma_f32_16x16x32_bf16(af, bf, acc[j], 0, 0, 0);
        }
    }

    // ---- epilogue: bias + resid, then per-row LayerNorm
    const int lq = lane >> 4;
    #pragma unroll
    for (int j = 0; j < 8; j++) {
        int col = wc * 128 + j * 16 + lm;
        float bv = bias[col];
        #pragma unroll
        for (int r = 0; r < 4; r++) {
            int row = m0 + wr * 16 + lq * 4 + r;
            acc[j][r] += bv + resid[(size_t)row * DD + col];
        }
    }
    #pragma unroll
    for (int r = 0; r < 4; r++) {
        float s = 0.f;
        #pragma unroll
        for (int j = 0; j < 8; j++) s += acc[j][r];
        s += __shfl_xor(s, 1, 64); s += __shfl_xor(s, 2, 64);
        s += __shfl_xor(s, 4, 64); s += __shfl_xor(s, 8, 64);
        if (lm == 0) rsum[wc * 32 + wr * 16 + lq * 4 + r] = s;
    }
    __syncthreads();
    float mean_[4];
    #pragma unroll
    for (int r = 0; r < 4; r++) {
        int ri = wr * 16 + lq * 4 + r;
        mean_[r] = (rsum[ri] + rsum[32 + ri]) * (1.0f / 256.0f);
    }
    #pragma unroll
    for (int r = 0; r < 4; r++) {
        float s2 = 0.f;
        #pragma unroll
        for (int j = 0; j < 8; j++) {
            float d = acc[j][r] - mean_[r];
            s2 += d * d;
        }
        s2 += __shfl_xor(s2, 1, 64); s2 += __shfl_xor(s2, 2, 64);
        s2 += __shfl_xor(s2, 4, 64); s2 += __shfl_xor(s2, 8, 64);
        if (lm == 0) rsum2[wc * 32 + wr * 16 + lq * 4 + r] = s2;
    }
    __syncthreads();
    float rstd[4];
    #pragma unroll
    for (int r = 0; r < 4; r++) {
        int ri = wr * 16 + lq * 4 + r;
        rstd[r] = rsqrtf((rsum2[ri] + rsum2[32 + ri]) * (1.0f / 256.0f) + 1e-5f);
    }
    #pragma unroll
    for (int j = 0; j < 8; j++) {
        int col = wc * 128 + j * 16 + lm;
        float gv = g[col], bv2 = bt[col];
        #pragma unroll
        for (int r = 0; r < 4; r++) {
            int row = m0 + wr * 16 + lq * 4 + r;
            float ov = (acc[j][r] - mean_[r]) * rstd[r] * gv + bv2;
            size_t idx = (size_t)row * DD + col;
            if (outf) outf[idx] = ov;
            if (outb) outb[idx] = f2bfu(ov);
        }
    }
    __syncthreads();
}

// ---------------------------------------------------------------------------
// Phase: l0 full attention, hi/lo scores + online softmax, split-K partials.
__device__ __forceinline__ void dev_attn_split(
    int vb, char* sm,
    const ushort_t* __restrict__ qkvh, const ushort_t* __restrict__ qkvl,
    const ushort_t* __restrict__ vth,
    float* __restrict__ Of, float2* __restrict__ Ml)
{
    ushort_t* Ks  = (ushort_t*)sm;               // 5120
    ushort_t* Vt  = (ushort_t*)(sm + 5120);      // 4608 -> 9728
    ushort_t* Ps  = (ushort_t*)(sm + 9728);      // 9216 -> 18944
    ushort_t* Ksl = (ushort_t*)(sm + 18944);     // 5120 -> 24064

    const int t = threadIdx.x;
    const int wave = t >> 6, lane = t & 63;
    const int lm = lane & 15, quad = lane >> 4;
    const int i0 = (vb & 15) * 64, h = (vb >> 4) & 7;
    const int z = vb >> 7;
    const int b = z >> 2, seg = z & (NSEG - 1);
    const int sr = t >> 2, sc8 = (t & 3) * 8;
    const int vd = t >> 3, vs8 = (t & 7) * 8;

    const size_t qoff = ((size_t)(b * SS) + i0 + 16 * wave + lm) * D3 + h * HD + quad * 8;
    short8 qh = *(const short8*)(qkvh + qoff);
    short8 ql = *(const short8*)(qkvl + qoff);

    const ushort_t* Kg  = qkvh + (size_t)(b * SS) * D3 + DD + h * HD;
    const ushort_t* Klg = qkvl + (size_t)(b * SS) * D3 + DD + h * HD;
    const ushort_t* Vg  = vth + ((size_t)b * HH + h) * HD * SS;

    float m[4], l[4];
    f32x4 o[2];
    #pragma unroll
    for (int r = 0; r < 4; r++) { m[r] = -1e30f; l[r] = 0.f; }
    o[0] = (f32x4){0.f, 0.f, 0.f, 0.f};
    o[1] = (f32x4){0.f, 0.f, 0.f, 0.f};

    const int per = (SS / 64) / NSEG;
    const int s0 = seg * per, s1 = s0 + per - 1;
    const float scl = 0.17677669529663688f;  // 1/sqrt(32)

    short8 kreg  = *(const short8*)(Kg  + (size_t)(s0 * 64 + sr) * D3 + sc8);
    short8 kregl = *(const short8*)(Klg + (size_t)(s0 * 64 + sr) * D3 + sc8);
    short8 vreg  = *(const short8*)(Vg  + (size_t)vd * SS + s0 * 64 + vs8);

    for (int kt = s0; kt <= s1; kt++) {
        const int k0 = kt * 64;
        __syncthreads();
        *(short8*)&Ks [sr * 40 + sc8] = kreg;
        *(short8*)&Ksl[sr * 40 + sc8] = kregl;
        *(short8*)&Vt [vd * 72 + vs8] = vreg;
        __syncthreads();
        if (kt < s1) {
            kreg  = *(const short8*)(Kg  + (size_t)(k0 + 64 + sr) * D3 + sc8);
            kregl = *(const short8*)(Klg + (size_t)(k0 + 64 + sr) * D3 + sc8);
            vreg  = *(const short8*)(Vg  + (size_t)vd * SS + k0 + 64 + vs8);
        }

        f32x4 s[4];
        #pragma unroll
        for (int cb = 0; cb < 4; cb++) {
            short8 kf  = *(const short8*)&Ks [(16 * cb + lm) * 40 + quad * 8];
            short8 kfl = *(const short8*)&Ksl[(16 * cb + lm) * 40 + quad * 8];
            f32x4 a = (f32x4){0.f, 0.f, 0.f, 0.f};
            a = __builtin_amdgcn_mfma_f32_16x16x32_bf16(ql, kf,  a, 0, 0, 0);
            a = __builtin_amdgcn_mfma_f32_16x16x32_bf16(qh, kfl, a, 0, 0, 0);
            a = __builtin_amdgcn_mfma_f32_16x16x32_bf16(qh, kf,  a, 0, 0, 0);
            s[cb] = a;
        }

        #pragma unroll
        for (int r = 0; r < 4; r++) {
            float s0r = s[0][r] * scl, s1r = s[1][r] * scl;
            float s2r = s[2][r] * scl, s3r = s[3][r] * scl;
            float tm = fmaxf(fmaxf(s0r, s1r), fmaxf(s2r, s3r));
            tm = fmaxf(tm, __shfl_xor(tm, 1, 64));
            tm = fmaxf(tm, __shfl_xor(tm, 2, 64));
            tm = fmaxf(tm, __shfl_xor(tm, 4, 64));
            tm = fmaxf(tm, __shfl_xor(tm, 8, 64));
            float mn = fmaxf(m[r], tm);
            float alpha = __expf(m[r] - mn);
            float p0 = __expf(s0r - mn), p1 = __expf(s1r - mn);
            float p2 = __expf(s2r - mn), p3 = __expf(s3r - mn);
            float ps = p0 + p1 + p2 + p3;
            ps += __shfl_xor(ps, 1, 64);
            ps += __shfl_xor(ps, 2, 64);
            ps += __shfl_xor(ps, 4, 64);
            ps += __shfl_xor(ps, 8, 64);
            l[r] = l[r] * alpha + ps;
            o[0][r] *= alpha;
            o[1][r] *= alpha;
            m[r] = mn;
            const int pr = (16 * wave + quad * 4 + r) * 72 + lm;
            Ps[pr +  0] = f2bfu(p0);
            Ps[pr + 16] = f2bfu(p1);
            Ps[pr + 32] = f2bfu(p2);
            Ps[pr + 48] = f2bfu(p3);
        }

        #pragma unroll
        for (int kc = 0; kc < 2; kc++) {
            short8 pf = *(const short8*)&Ps[(16 * wave + lm) * 72 + 32 * kc + quad * 8];
            #pragma unroll
            for (int nh = 0; nh < 2; nh++) {
                short8 vf = *(const short8*)&Vt[(16 * nh + lm) * 72 + 32 * kc + quad * 8];
                o[nh] = __builtin_amdgcn_mfma_f32_16x16x32_bf16(pf, vf, o[nh], 0, 0, 0);
            }
        }
    }

    #pragma unroll
    for (int r = 0; r < 4; r++) {
        int row = i0 + 16 * wave + quad * 4 + r;
        size_t base = ((size_t)seg * NTOK + b * SS + row) * DD + h * HD + lm;
        Of[base]      = o[0][r];
        Of[base + 16] = o[1][r];
        if (lm == 0)
            Ml[((size_t)seg * NTOK + b * SS + row) * HH + h] =
                make_float2(m[r], l[r]);
    }
    __syncthreads();
}

// ---------------------------------------------------------------------------
// Phase: fixed-max attention (post-LN inputs; scores O(1)).
__device__ __forceinline__ void dev_attn_fixed(
    int vb, char* sm,
    const ushort_t* __restrict__ qkvh, const ushort_t* __restrict__ vth,
    ushort_t* __restrict__ outb,
    float* __restrict__ Of, float2* __restrict__ Ml,
    int win, int nseg)
{
    ushort_t* Ks = (ushort_t*)sm;               // 5120
    ushort_t* Vt = (ushort_t*)(sm + 5120);      // 4608
    ushort_t* Ps = (ushort_t*)(sm + 9728);      // 9216

    const int t = threadIdx.x;
    const int wave = t >> 6, lane = t & 63;
    const int lm = lane & 15, quad = lane >> 4;
    const int i0 = (vb & 15) * 64, h = (vb >> 4) & 7;
    const int z = vb >> 7;
    const int b = z / nseg, seg = z - b * nseg;
    const int sr = t >> 2, sc8 = (t & 3) * 8;
    const int vd = t >> 3, vs8 = (t & 7) * 8;

    const size_t qoff = ((size_t)(b * SS) + i0 + 16 * wave + lm) * D3 + h * HD + quad * 8;
    short8 qh = *(const short8*)(qkvh + qoff);

    const ushort_t* Kg = qkvh + (size_t)(b * SS) * D3 + DD + h * HD;
    const ushort_t* Vg = vth + ((size_t)b * HH + h) * HD * SS;

    float l[4] = {0.f, 0.f, 0.f, 0.f};
    f32x4 o[2];
    o[0] = (f32x4){0.f, 0.f, 0.f, 0.f};
    o[1] = (f32x4){0.f, 0.f, 0.f, 0.f};

    int t0 = 0, t1 = SS / 64 - 1;
    const bool masked = (win < SS);
    if (masked) {
        t0 = (i0 - win) >> 6;        if (t0 < 0) t0 = 0;
        t1 = (i0 + 63 + win) >> 6;   if (t1 > SS / 64 - 1) t1 = SS / 64 - 1;
    }
    const int per = (t1 - t0 + nseg) / nseg;
    const int s0 = t0 + seg * per;
    const int s1 = (s0 + per - 1 < t1) ? (s0 + per - 1) : t1;
    const float scl = 0.17677669529663688f;  // 1/sqrt(32)
    const float M0 = 32.0f;                   // fixed softmax shift

    short8 kreg = *(const short8*)(Kg + (size_t)(s0 * 64 + sr) * D3 + sc8);
    short8 vreg = *(const short8*)(Vg + (size_t)vd * SS + s0 * 64 + vs8);

    for (int kt = s0; kt <= s1; kt++) {
        const int k0 = kt * 64;
        __syncthreads();
        *(short8*)&Ks[sr * 40 + sc8] = kreg;
        *(short8*)&Vt[vd * 72 + vs8] = vreg;
        __syncthreads();
        if (kt < s1) {
            kreg = *(const short8*)(Kg + (size_t)(k0 + 64 + sr) * D3 + sc8);
            vreg = *(const short8*)(Vg + (size_t)vd * SS + k0 + 64 + vs8);
        }

        f32x4 s[4];
        #pragma unroll
        for (int cb = 0; cb < 4; cb++) {
            short8 kf = *(const short8*)&Ks[(16 * cb + lm) * 40 + quad * 8];
            f32x4 a = (f32x4){0.f, 0.f, 0.f, 0.f};
            a = __builtin_amdgcn_mfma_f32_16x16x32_bf16(qh, kf, a, 0, 0, 0);
            s[cb] = a;
        }

        #pragma unroll
        for (int r = 0; r < 4; r++) {
            float p[4];
            #pragma unroll
            for (int cb = 0; cb < 4; cb++) {
                float v = s[cb][r] * scl;
                if (masked) {
                    int di = (i0 + 16 * wave + quad * 4 + r) - (k0 + 16 * cb + lm);
                    if (di > win || di < -win) v = -1e30f;
                }
                p[cb] = __expf(v - M0);
            }
            l[r] += p[0] + p[1] + p[2] + p[3];
            const int pr = (16 * wave + quad * 4 + r) * 72 + lm;
            Ps[pr +  0] = f2bfu(p[0]);
            Ps[pr + 16] = f2bfu(p[1]);
            Ps[pr + 32] = f2bfu(p[2]);
            Ps[pr + 48] = f2bfu(p[3]);
        }
        // Ps region is wave-private — no barrier needed

        #pragma unroll
        for (int kc = 0; kc < 2; kc++) {
            short8 pf = *(const short8*)&Ps[(16 * wave + lm) * 72 + 32 * kc + quad * 8];
            #pragma unroll
            for (int nh = 0; nh < 2; nh++) {
                short8 vf = *(const short8*)&Vt[(16 * nh + lm) * 72 + 32 * kc + quad * 8];
                o[nh] = __builtin_amdgcn_mfma_f32_16x16x32_bf16(pf, vf, o[nh], 0, 0, 0);
            }
        }
    }

    #pragma unroll
    for (int r = 0; r < 4; r++) {
        l[r] += __shfl_xor(l[r], 1, 64);
        l[r] += __shfl_xor(l[r], 2, 64);
        l[r] += __shfl_xor(l[r], 4, 64);
        l[r] += __shfl_xor(l[r], 8, 64);
    }

    if (nseg == 1) {
        #pragma unroll
        for (int r = 0; r < 4; r++) {
            float invl = 1.0f / l[r];
            size_t base = ((size_t)(b * SS) + i0 + 16 * wave + quad * 4 + r) * DD + h * HD + lm;
            outb[base]      = f2bfu(o[0][r] * invl);
            outb[base + 16] = f2bfu(o[1][r] * invl);
        }
    } else {
        #pragma unroll
        for (int r = 0; r < 4; r++) {
            int row = i0 + 16 * wave + quad * 4 + r;
            size_t base = ((size_t)seg * NTOK + b * SS + row) * DD + h * HD + lm;
            Of[base]      = o[0][r];
            Of[base + 16] = o[1][r];
            if (lm == 0)
                Ml[((size_t)seg * NTOK + b * SS + row) * HH + h] =
                    make_float2(M0, l[r]);
        }
    }
    __syncthreads();
}

// ---------------------------------------------------------------------------
// The megakernel: 17 phases separated by device-wide barriers.
__global__ __launch_bounds__(256, 2) void megakernel(MegaArgs A)
{
    __shared__ __align__(16) char sm[30720];

    ushort_t* WinA_b  = A.Wb + 0;
    ushort_t* WoutA_b = A.Wb + 393216;
    ushort_t* WinE_b  = A.Wb + 524288;
    ushort_t* WoutE_b = A.Wb + 917504;
    ushort_t* W1_b    = A.Wb + 1048576;
    ushort_t* W2_b    = A.Wb + 1572864;

    float* cur = A.X;           float* oth = A.X2;
    ushort_t* curb = A.Xb;      ushort_t* othb = A.X2b;

    int ph = 0;

    // Phase 0: prep
    for (int vb = blockIdx.x; vb < WBLK + PBLK; vb += GRID) dev_prep(vb, A);

    for (int l = 0; l < 2; l++) {
        gbar(A.bar, ph++);
        // QKV projection (full-attention weights)
        if (l == 0) {
            for (int vb = blockIdx.x; vb < 6 * 64; vb += GRID)
                dev_gemm_split(vb % 6, vb / 6, sm, A.Xb, A.Xlb, WinA_b, A.Wl0,
                               A.bin_a, A.QKVb, A.QKVl, A.VTh, D3, DD);
        } else {
            for (int vb = blockIdx.x; vb < 6 * 64; vb += GRID)
                dev_gemm(vb % 6, vb / 6, sm, curb, WinA_b + (size_t)l * D3 * DD,
                         A.bin_a + (size_t)l * D3, nullptr, nullptr, A.QKVb,
                         A.VTh, D3, DD, 0);
        }
        gbar(A.bar, ph++);
        // Full attention (split-K, NSEG)
        if (l == 0) {
            for (int vb = blockIdx.x; vb < 16 * 8 * BB * NSEG; vb += GRID)
                dev_attn_split(vb, sm, A.QKVb, A.QKVl, A.VTh, A.Of, A.Ml);
        } else {
            for (int vb = blockIdx.x; vb < 16 * 8 * BB * NSEG; vb += GRID)
                dev_attn_fixed(vb, sm, A.QKVb, A.VTh, nullptr, A.Of, A.Ml,
                               1 << 28, NSEG);
        }
        gbar(A.bar, ph++);
        // Wout + combine + LN1
        for (int vb = blockIdx.x; vb < NTOK / 32; vb += GRID)
            dev_gemm_ln<true>(vb, sm, nullptr, A.Of, A.Ml,
                              WoutA_b + (size_t)l * DD * DD,
                              A.bout_a + (size_t)l * DD, cur,
                              A.ln1_g + l * DD, A.ln1_b + l * DD, oth, othb, DD);
        gbar(A.bar, ph++);
        // Banded QKV
        for (int vb = blockIdx.x; vb < 6 * 64; vb += GRID)
            dev_gemm(vb % 6, vb / 6, sm, othb, WinE_b + (size_t)l * D3 * DD,
                     A.bin_e + (size_t)l * D3, nullptr, nullptr, A.QKVb,
                     A.VTh, D3, DD, 0);
        gbar(A.bar, ph++);
        // Banded attention (nseg=1)
        for (int vb = blockIdx.x; vb < 16 * 8 * BB; vb += GRID)
            dev_attn_fixed(vb, sm, A.QKVb, A.VTh, A.ATb, nullptr, nullptr, 64, 1);
        gbar(A.bar, ph++);
        // Wout_e + LN2
        for (int vb = blockIdx.x; vb < NTOK / 32; vb += GRID)
            dev_gemm_ln<false>(vb, sm, A.ATb, nullptr, nullptr,
                               WoutE_b + (size_t)l * DD * DD,
                               A.bout_e + (size_t)l * DD, oth,
                               A.ln2_g + l * DD, A.ln2_b + l * DD, cur, curb, DD);
        gbar(A.bar, ph++);
        // MLP W1 + gelu
        for (int vb = blockIdx.x; vb < 8 * 64; vb += GRID)
            dev_gemm(vb & 7, vb >> 3, sm, curb, W1_b + (size_t)l * MLP * DD,
                     A.b1 + (size_t)l * MLP, nullptr, nullptr, A.HMLb,
                     nullptr, MLP, DD, 1);
        gbar(A.bar, ph++);
        // MLP W2 (+ final LN on layer 1)
        if (l == 0) {
            for (int vb = blockIdx.x; vb < 2 * 64; vb += GRID)
                dev_gemm(vb & 1, vb >> 1, sm, A.HMLb, W2_b, A.b2, cur,
                         oth, othb, nullptr, DD, MLP, 0);
            float* tf = cur; cur = oth; oth = tf;
            ushort_t* tb = curb; curb = othb; othb = tb;
        } else {
            for (int vb = blockIdx.x; vb < NTOK / 32; vb += GRID)
                dev_gemm_ln<false>(vb, sm, A.HMLb, nullptr, nullptr,
                                   W2_b + (size_t)l * DD * MLP,
                                   A.b2 + (size_t)l * DD, cur,
                                   A.lnf_g, A.lnf_b, A.dout, nullptr, MLP);
        }
    }
}

// ---------------------------------------------------------------------------
extern "C" void kernel_launch(void* const* d_in, const int* in_sizes, int n_in,
                              void* d_out, int out_size, void* d_ws, size_t ws_size,
                              hipStream_t stream)
{
    MegaArgs a;
    a.xin    = (const float*)d_in[0];
    a.scale  = (const float*)d_in[1];
    a.Win_a  = (const float*)d_in[2];
    a.bin_a  = (const float*)d_in[3];
    a.Wout_a = (const float*)d_in[4];
    a.bout_a = (const float*)d_in[5];
    a.Win_e  = (const float*)d_in[6];
    a.bin_e  = (const float*)d_in[7];
    a.Wout_e = (const float*)d_in[8];
    a.bout_e = (const float*)d_in[9];
    a.ln1_g  = (const float*)d_in[10];
    a.ln1_b  = (const float*)d_in[11];
    a.ln2_g  = (const float*)d_in[12];
    a.ln2_b  = (const float*)d_in[13];
    a.W1     = (const float*)d_in[14];
    a.b1     = (const float*)d_in[15];
    a.W2     = (const float*)d_in[16];
    a.b2     = (const float*)d_in[17];
    a.lnf_g  = (const float*)d_in[18];
    a.lnf_b  = (const float*)d_in[19];

    char* ws = (char*)d_ws;
    a.bar  = (unsigned*)ws;         ws += 256;   // barrier state (zeroed below)
    a.X    = (float*)ws;            ws += (size_t)NTOK * DD * 4;
    a.X2   = (float*)ws;            ws += (size_t)NTOK * DD * 4;
    a.Xb   = (ushort_t*)ws;         ws += (size_t)NTOK * DD * 2;
    a.Xlb  = (ushort_t*)ws;         ws += (size_t)NTOK * DD * 2;
    a.X2b  = (ushort_t*)ws;         ws += (size_t)NTOK * DD * 2;
    a.ATb  = (ushort_t*)ws;         ws += (size_t)NTOK * DD * 2;
    a.QKVb = (ushort_t*)ws;         ws += (size_t)NTOK * D3 * 2;
    a.QKVl = (ushort_t*)ws;         ws += (size_t)NTOK * D3 * 2;
    a.VTh  = (ushort_t*)ws;         ws += (size_t)NTOK * DD * 2;
    a.HMLb = (ushort_t*)ws;         ws += (size_t)NTOK * MLP * 2;
    a.Wb   = (ushort_t*)ws;         ws += (size_t)W_TOT * 2;
    a.Wl0  = (ushort_t*)ws;         ws += (size_t)WL0 * 2;
    a.Ml   = (float2*)ws;           ws += (size_t)NSEG * NTOK * HH * 8;
    a.Of   = (float*)ws;            ws += (size_t)NSEG * NTOK * DD * 4;
    a.dout = (float*)d_out;

    hipMemsetAsync(a.bar, 0, 256, stream);
    megakernel<<<GRID, 256, 0, stream>>>(a);
}

// Round 16
// 334.509 us; speedup vs baseline: 5.5719x; 5.5719x over previous
//
#include <hip/hip_runtime.h>
#include <math.h>

// Problem constants
#define BB 4
#define SS 1024
#define DD 256
#define HH 8
#define HD 32
#define D3 768
#define MLP 1024
#define NTOK (BB * SS)   // 4096
#define NSEG 4           // split-K segments for full attention

typedef __attribute__((ext_vector_type(8))) short short8;
typedef __attribute__((ext_vector_type(4))) float f32x4;

__device__ __forceinline__ unsigned short f2bfu(float f) {
    union { float f; unsigned i; } u; u.f = f;
    unsigned r = u.i + 0x7fffu + ((u.i >> 16) & 1u);   // RNE
    return (unsigned short)(r >> 16);
}
__device__ __forceinline__ float bfu2f(unsigned short h) {
    union { unsigned i; float f; } u; u.i = ((unsigned)h) << 16; return u.f;
}

// ---------------------------------------------------------------------------
// Fused prep: weights fp32->bf16 (+lo for Win_a layer 0)  AND  x+pos encode.
#define W_TOT 2097152
#define WL0   196608   // 768*256 = Win_a layer 0
#define WBLK  (W_TOT / 256)          // 8192 weight blocks
#define PBLK  (NTOK * DD / 256)      // 4096 pos blocks
__global__ __launch_bounds__(256) void prep_kernel(
    const float* __restrict__ a0, const float* __restrict__ a1,
    const float* __restrict__ a2, const float* __restrict__ a3,
    const float* __restrict__ a4, const float* __restrict__ a5,
    unsigned short* __restrict__ out, unsigned short* __restrict__ out_lo,
    const float* __restrict__ x, const float* __restrict__ scale,
    float* __restrict__ xf, unsigned short* __restrict__ xh,
    unsigned short* __restrict__ xl)
{
    if (blockIdx.x < WBLK) {
        int i = blockIdx.x * 256 + threadIdx.x;
        const float* s; int off;
        if      (i <  393216) { s = a0; off = 0;       }
        else if (i <  524288) { s = a1; off = 393216;  }
        else if (i <  917504) { s = a2; off = 524288;  }
        else if (i < 1048576) { s = a3; off = 917504;  }
        else if (i < 1572864) { s = a4; off = 1048576; }
        else                  { s = a5; off = 1572864; }
        float v = s[i - off];
        unsigned short h = f2bfu(v);
        out[i] = h;
        if (i < WL0) out_lo[i] = f2bfu(v - bfu2f(h));
    } else {
        int i = (blockIdx.x - WBLK) * 256 + threadIdx.x;
        int s = (i >> 8) & (SS - 1);
        float v = x[i] + (float)s * scale[0];
        xf[i] = v;
        unsigned short h = f2bfu(v);
        xh[i] = h;
        xl[i] = f2bfu(v - bfu2f(h));
    }
}

// ---------------------------------------------------------------------------
// V-epilogue helper: token row + V-column -> VT[b][h][d][s] index
__device__ __forceinline__ size_t vt_index(int row, int col512) {
    int b = row >> 10, s = row & (SS - 1);
    int h = col512 >> 5, d = col512 & (HD - 1);
    return (((size_t)b * HH + h) * HD + d) * SS + s;
}

// ---------------------------------------------------------------------------
// MFMA GEMM: C[M,N] = A[M,K](bf16) @ W[N,K]^T(bf16) + bias(f32)
//            [+gelu] [+resid f32] -> outf (f32) and/or outb (bf16)
// If vth != null (QKV proj): cols >= 512 go transposed to VT[b][h][d][s].
// 64x128 block tile, 256 thr = 4 waves (2x2 of 32x64), BK=32, reg prefetch.
#define LDP 40
__global__ __launch_bounds__(256) void gemm_mfma(
    const unsigned short* __restrict__ A, const unsigned short* __restrict__ W,
    const float* __restrict__ bias, const float* __restrict__ resid,
    float* __restrict__ outf, unsigned short* __restrict__ outb,
    unsigned short* __restrict__ vth,
    int M, int N, int K, int act)
{
    __shared__ __align__(16) unsigned short As[64 * LDP];
    __shared__ __align__(16) unsigned short Bs[128 * LDP];
    const int t = threadIdx.x;
    const int lane = t & 63, wave = t >> 6;
    const int wr = wave >> 1, wc = wave & 1;
    const int m0 = blockIdx.y * 64, n0 = blockIdx.x * 128;
    const int sr = t >> 2;
    const int sc = (t & 3) * 8;

    const unsigned short* Ag = A + (size_t)(m0 + sr) * K + sc;
    const unsigned short* Wg = W + (size_t)(n0 + sr) * K + sc;

    f32x4 acc[2][4];
    #pragma unroll
    for (int i = 0; i < 2; i++)
        #pragma unroll
        for (int j = 0; j < 4; j++)
            acc[i][j] = (f32x4){0.f, 0.f, 0.f, 0.f};

    const int lm = lane & 15, lk = (lane >> 4) * 8;

    uint4 a0 = *(const uint4*)(Ag);
    uint4 b0 = *(const uint4*)(Wg);
    uint4 b1 = *(const uint4*)(Wg + (size_t)64 * K);

    for (int k0 = 0; k0 < K; k0 += 32) {
        __syncthreads();
        *(uint4*)&As[sr * LDP + sc]        = a0;
        *(uint4*)&Bs[sr * LDP + sc]        = b0;
        *(uint4*)&Bs[(sr + 64) * LDP + sc] = b1;
        __syncthreads();
        if (k0 + 32 < K) {
            a0 = *(const uint4*)(Ag + k0 + 32);
            b0 = *(const uint4*)(Wg + k0 + 32);
            b1 = *(const uint4*)(Wg + (size_t)64 * K + k0 + 32);
        }

        short8 af[2], bf[4];
        #pragma unroll
        for (int i = 0; i < 2; i++)
            af[i] = *(const short8*)&As[(wr * 32 + i * 16 + lm) * LDP + lk];
        #pragma unroll
        for (int j = 0; j < 4; j++)
            bf[j] = *(const short8*)&Bs[(wc * 64 + j * 16 + lm) * LDP + lk];
        #pragma unroll
        for (int i = 0; i < 2; i++)
            #pragma unroll
            for (int j = 0; j < 4; j++)
                acc[i][j] = __builtin_amdgcn_mfma_f32_16x16x32_bf16(
                    af[i], bf[j], acc[i][j], 0, 0, 0);
    }

    const int lq = lane >> 4;
    #pragma unroll
    for (int j = 0; j < 4; j++) {
        int col = n0 + wc * 64 + j * 16 + lm;
        float bv = bias[col];
        #pragma unroll
        for (int i = 0; i < 2; i++) {
            #pragma unroll
            for (int r = 0; r < 4; r++) {
                int row = m0 + wr * 32 + i * 16 + lq * 4 + r;
                float v = acc[i][j][r] + bv;
                if (act) v = 0.5f * v * (1.0f + erff(v * 0.70710678118654752f));
                if (vth && col >= 2 * DD) {
                    vth[vt_index(row, col - 2 * DD)] = f2bfu(v);
                } else {
                    size_t idx = (size_t)row * N + col;
                    if (resid) v += resid[idx];
                    if (outf) outf[idx] = v;
                    if (outb) outb[idx] = f2bfu(v);
                }
            }
        }
    }
}

// ---------------------------------------------------------------------------
// Full-row GEMM (N=256) + residual + LayerNorm fused epilogue.
// COMBINE: A built from split-K attention partials (Of, Ml) with softmax
// combine+normalize in the staging path; else A is plain bf16.
// 16x256 block tile (grid NTOK/16 = 256 blocks — full machine), 4 waves
// each computing 16x64, BK=32.
template<bool COMBINE>
__global__ __launch_bounds__(256) void gemm_ln(
    const unsigned short* __restrict__ A,
    const float* __restrict__ Of, const float2* __restrict__ Ml,
    const unsigned short* __restrict__ W, const float* __restrict__ bias,
    const float* __restrict__ resid,
    const float* __restrict__ g, const float* __restrict__ bt,
    float* __restrict__ outf, unsigned short* __restrict__ outb, int K)
{
    __shared__ __align__(16) unsigned short As[16 * LDP];    // 1.3 KB
    __shared__ __align__(16) unsigned short Bs[256 * LDP];   // 20.5 KB
    __shared__ float rsum[4][16];
    __shared__ float rsum2[4][16];
    const int t = threadIdx.x;
    const int lane = t & 63, wave = t >> 6;
    const int m0 = blockIdx.x * 16;
    const int sr = t >> 2;          // 0..63 (B staging rows, x4 strided)
    const int sc = (t & 3) * 8;
    const int arow = t >> 2;        // A staging uses t<64: rows 0..15
    const int acol = (t & 3) * 8;

    const unsigned short* Wg = W + (size_t)sr * K + sc;

    f32x4 acc[4];
    #pragma unroll
    for (int j = 0; j < 4; j++) acc[j] = (f32x4){0.f, 0.f, 0.f, 0.f};

    const int lm = lane & 15, lk = (lane >> 4) * 8;
    const int quad = lane >> 4;

    for (int k0 = 0; k0 < K; k0 += 32) {
        unsigned short ab[8];
        const bool aload = (t < 64);
        if (aload) {
            const int token = m0 + arow;
            if (COMBINE) {
                const int h = (k0 + acol) >> 5;
                float2 ml[NSEG];
                float M = -1e30f;
                #pragma unroll
                for (int s = 0; s < NSEG; s++) {
                    ml[s] = Ml[((size_t)s * NTOK + token) * HH + h];
                    M = fmaxf(M, ml[s].x);
                }
                float wgt[NSEG]; float denom = 0.f;
                #pragma unroll
                for (int s = 0; s < NSEG; s++) {
                    wgt[s] = __expf(ml[s].x - M);
                    denom += ml[s].y * wgt[s];
                }
                const float inv = 1.0f / denom;
                float a8[8] = {};
                #pragma unroll
                for (int s = 0; s < NSEG; s++) {
                    const float* p = Of + ((size_t)s * NTOK + token) * DD + k0 + acol;
                    float4 x0 = *(const float4*)p;
                    float4 x1 = *(const float4*)(p + 4);
                    a8[0] += x0.x * wgt[s]; a8[1] += x0.y * wgt[s];
                    a8[2] += x0.z * wgt[s]; a8[3] += x0.w * wgt[s];
                    a8[4] += x1.x * wgt[s]; a8[5] += x1.y * wgt[s];
                    a8[6] += x1.z * wgt[s]; a8[7] += x1.w * wgt[s];
                }
                #pragma unroll
                for (int c = 0; c < 8; c++) ab[c] = f2bfu(a8[c] * inv);
            } else {
                uint4 av = *(const uint4*)(A + (size_t)(m0 + arow) * K + k0 + acol);
                *(uint4*)ab = av;
            }
        }
        uint4 b0 = *(const uint4*)(Wg + k0);
        uint4 b1 = *(const uint4*)(Wg + (size_t)64 * K + k0);
        uint4 b2 = *(const uint4*)(Wg + (size_t)128 * K + k0);
        uint4 b3 = *(const uint4*)(Wg + (size_t)192 * K + k0);
        __syncthreads();
        if (aload) *(uint4*)&As[arow * LDP + acol] = *(uint4*)ab;
        *(uint4*)&Bs[sr * LDP + sc]         = b0;
        *(uint4*)&Bs[(sr + 64) * LDP + sc]  = b1;
        *(uint4*)&Bs[(sr + 128) * LDP + sc] = b2;
        *(uint4*)&Bs[(sr + 192) * LDP + sc] = b3;
        __syncthreads();

        short8 af = *(const short8*)&As[lm * LDP + lk];
        #pragma unroll
        for (int j = 0; j < 4; j++) {
            short8 bf = *(const short8*)&Bs[(wave * 64 + j * 16 + lm) * LDP + lk];
            acc[j] = __builtin_amdgcn_mfma_f32_16x16x32_bf16(af, bf, acc[j], 0, 0, 0);
        }
    }

    // ---- epilogue: bias + resid, then per-row LayerNorm.
    // Wave w holds rows (quad*4+r) x cols (64w + 16j + lm).
    #pragma unroll
    for (int j = 0; j < 4; j++) {
        int col = wave * 64 + j * 16 + lm;
        float bv = bias[col];
        #pragma unroll
        for (int r = 0; r < 4; r++) {
            int row = m0 + quad * 4 + r;
            acc[j][r] += bv + resid[(size_t)row * DD + col];
        }
    }
    #pragma unroll
    for (int r = 0; r < 4; r++) {
        float s = 0.f;
        #pragma unroll
        for (int j = 0; j < 4; j++) s += acc[j][r];
        s += __shfl_xor(s, 1, 64); s += __shfl_xor(s, 2, 64);
        s += __shfl_xor(s, 4, 64); s += __shfl_xor(s, 8, 64);
        if (lm == 0) rsum[wave][quad * 4 + r] = s;
    }
    __syncthreads();
    float mean_[4];
    #pragma unroll
    for (int r = 0; r < 4; r++) {
        int ri = quad * 4 + r;
        mean_[r] = (rsum[0][ri] + rsum[1][ri] + rsum[2][ri] + rsum[3][ri])
                 * (1.0f / 256.0f);
    }
    #pragma unroll
    for (int r = 0; r < 4; r++) {
        float s2 = 0.f;
        #pragma unroll
        for (int j = 0; j < 4; j++) {
            float d = acc[j][r] - mean_[r];
            s2 += d * d;
        }
        s2 += __shfl_xor(s2, 1, 64); s2 += __shfl_xor(s2, 2, 64);
        s2 += __shfl_xor(s2, 4, 64); s2 += __shfl_xor(s2, 8, 64);
        if (lm == 0) rsum2[wave][quad * 4 + r] = s2;
    }
    __syncthreads();
    float rstd[4];
    #pragma unroll
    for (int r = 0; r < 4; r++) {
        int ri = quad * 4 + r;
        rstd[r] = rsqrtf((rsum2[0][ri] + rsum2[1][ri] + rsum2[2][ri] + rsum2[3][ri])
                         * (1.0f / 256.0f) + 1e-5f);
    }
    #pragma unroll
    for (int j = 0; j < 4; j++) {
        int col = wave * 64 + j * 16 + lm;
        float gv = g[col], bv2 = bt[col];
        #pragma unroll
        for (int r = 0; r < 4; r++) {
            int row = m0 + quad * 4 + r;
            float ov = (acc[j][r] - mean_[r]) * rstd[r] * gv + bv2;
            size_t idx = (size_t)row * DD + col;
            if (outf) outf[idx] = ov;
            if (outb) outb[idx] = f2bfu(ov);
        }
    }
}

// ---------------------------------------------------------------------------
// Split (hi/lo bf16 ~ fp32) MFMA GEMM for the layer-0 QKV projection.
// Q,K -> packed hi/lo; V -> transposed VT (hi only). Register-prefetched.
__global__ __launch_bounds__(256) void gemm_mfma_split(
    const unsigned short* __restrict__ Ah, const unsigned short* __restrict__ Al,
    const unsigned short* __restrict__ Wh, const unsigned short* __restrict__ Wl,
    const float* __restrict__ bias,
    unsigned short* __restrict__ outh, unsigned short* __restrict__ outl,
    unsigned short* __restrict__ vth,
    int M, int N, int K)
{
    __shared__ __align__(16) unsigned short Ash[64 * LDP];
    __shared__ __align__(16) unsigned short Asl[64 * LDP];
    __shared__ __align__(16) unsigned short Bsh[128 * LDP];
    __shared__ __align__(16) unsigned short Bsl[128 * LDP];
    const int t = threadIdx.x;
    const int lane = t & 63, wave = t >> 6;
    const int wr = wave >> 1, wc = wave & 1;
    const int m0 = blockIdx.y * 64, n0 = blockIdx.x * 128;
    const int sr = t >> 2;
    const int sc = (t & 3) * 8;

    const size_t oA = (size_t)(m0 + sr) * K + sc;
    const size_t oW = (size_t)(n0 + sr) * K + sc;

    f32x4 acc[2][4];
    #pragma unroll
    for (int i = 0; i < 2; i++)
        #pragma unroll
        for (int j = 0; j < 4; j++)
            acc[i][j] = (f32x4){0.f, 0.f, 0.f, 0.f};

    const int lm = lane & 15, lk = (lane >> 4) * 8;

    uint4 ah0 = *(const uint4*)(Ah + oA);
    uint4 al0 = *(const uint4*)(Al + oA);
    uint4 bh0 = *(const uint4*)(Wh + oW);
    uint4 bh1 = *(const uint4*)(Wh + oW + (size_t)64 * K);
    uint4 bl0 = *(const uint4*)(Wl + oW);
    uint4 bl1 = *(const uint4*)(Wl + oW + (size_t)64 * K);

    for (int k0 = 0; k0 < K; k0 += 32) {
        __syncthreads();
        *(uint4*)&Ash[sr * LDP + sc]        = ah0;
        *(uint4*)&Asl[sr * LDP + sc]        = al0;
        *(uint4*)&Bsh[sr * LDP + sc]        = bh0;
        *(uint4*)&Bsh[(sr + 64) * LDP + sc] = bh1;
        *(uint4*)&Bsl[sr * LDP + sc]        = bl0;
        *(uint4*)&Bsl[(sr + 64) * LDP + sc] = bl1;
        __syncthreads();
        if (k0 + 32 < K) {
            ah0 = *(const uint4*)(Ah + oA + k0 + 32);
            al0 = *(const uint4*)(Al + oA + k0 + 32);
            bh0 = *(const uint4*)(Wh + oW + k0 + 32);
            bh1 = *(const uint4*)(Wh + oW + (size_t)64 * K + k0 + 32);
            bl0 = *(const uint4*)(Wl + oW + k0 + 32);
            bl1 = *(const uint4*)(Wl + oW + (size_t)64 * K + k0 + 32);
        }

        short8 afh[2], afl[2], bfh[4], bfl[4];
        #pragma unroll
        for (int i = 0; i < 2; i++) {
            afh[i] = *(const short8*)&Ash[(wr * 32 + i * 16 + lm) * LDP + lk];
            afl[i] = *(const short8*)&Asl[(wr * 32 + i * 16 + lm) * LDP + lk];
        }
        #pragma unroll
        for (int j = 0; j < 4; j++) {
            bfh[j] = *(const short8*)&Bsh[(wc * 64 + j * 16 + lm) * LDP + lk];
            bfl[j] = *(const short8*)&Bsl[(wc * 64 + j * 16 + lm) * LDP + lk];
        }
        #pragma unroll
        for (int i = 0; i < 2; i++)
            #pragma unroll
            for (int j = 0; j < 4; j++) {
                acc[i][j] = __builtin_amdgcn_mfma_f32_16x16x32_bf16(
                    afl[i], bfh[j], acc[i][j], 0, 0, 0);
                acc[i][j] = __builtin_amdgcn_mfma_f32_16x16x32_bf16(
                    afh[i], bfl[j], acc[i][j], 0, 0, 0);
                acc[i][j] = __builtin_amdgcn_mfma_f32_16x16x32_bf16(
                    afh[i], bfh[j], acc[i][j], 0, 0, 0);
            }
    }

    const int lq = lane >> 4;
    #pragma unroll
    for (int j = 0; j < 4; j++) {
        int col = n0 + wc * 64 + j * 16 + lm;
        float bv = bias[col];
        #pragma unroll
        for (int i = 0; i < 2; i++) {
            #pragma unroll
            for (int r = 0; r < 4; r++) {
                int row = m0 + wr * 32 + i * 16 + lq * 4 + r;
                float v = acc[i][j][r] + bv;
                unsigned short h = f2bfu(v);
                if (col >= 2 * DD) {
                    vth[vt_index(row, col - 2 * DD)] = h;
                } else {
                    size_t idx = (size_t)row * N + col;
                    outh[idx] = h;
                    outl[idx] = f2bfu(v - bfu2f(h));
                }
            }
        }
    }
}

// ---------------------------------------------------------------------------
// MFMA flash attention, SPLIT (hi/lo) scores with ONLINE softmax — layer-0
// full attention only. V hi-only (lo term <= bf16-rounding of O). Split-K.
__global__ __launch_bounds__(256) void attn_split(
    const unsigned short* __restrict__ qkvh,
    const unsigned short* __restrict__ qkvl,
    const unsigned short* __restrict__ vth,
    float* __restrict__ Of, float2* __restrict__ Ml)
{
    __shared__ __align__(16) unsigned short Ks [64 * 40];
    __shared__ __align__(16) unsigned short Vt [32 * 72];
    __shared__ __align__(16) unsigned short Ps [64 * 72];
    __shared__ __align__(16) unsigned short Ksl[64 * 40];

    const int t = threadIdx.x;
    const int wave = t >> 6, lane = t & 63;
    const int lm = lane & 15, quad = lane >> 4;
    const int i0 = blockIdx.x * 64, h = blockIdx.y;
    const int z = blockIdx.z;
    const int b = z >> 2, seg = z & (NSEG - 1);
    const int sr = t >> 2, sc8 = (t & 3) * 8;
    const int vd = t >> 3, vs8 = (t & 7) * 8;

    const size_t qoff = ((size_t)(b * SS) + i0 + 16 * wave + lm) * D3 + h * HD + quad * 8;
    short8 qh = *(const short8*)(qkvh + qoff);
    short8 ql = *(const short8*)(qkvl + qoff);

    const unsigned short* Kg  = qkvh + (size_t)(b * SS) * D3 + DD + h * HD;
    const unsigned short* Klg = qkvl + (size_t)(b * SS) * D3 + DD + h * HD;
    const unsigned short* Vg  = vth + ((size_t)b * HH + h) * HD * SS;

    float m[4], l[4];
    f32x4 o[2];
    #pragma unroll
    for (int r = 0; r < 4; r++) { m[r] = -1e30f; l[r] = 0.f; }
    o[0] = (f32x4){0.f, 0.f, 0.f, 0.f};
    o[1] = (f32x4){0.f, 0.f, 0.f, 0.f};

    const int per = (SS / 64) / NSEG;
    const int s0 = seg * per, s1 = s0 + per - 1;
    const float scl = 0.17677669529663688f;  // 1/sqrt(32)

    short8 kreg  = *(const short8*)(Kg  + (size_t)(s0 * 64 + sr) * D3 + sc8);
    short8 kregl = *(const short8*)(Klg + (size_t)(s0 * 64 + sr) * D3 + sc8);
    short8 vreg  = *(const short8*)(Vg  + (size_t)vd * SS + s0 * 64 + vs8);

    for (int kt = s0; kt <= s1; kt++) {
        const int k0 = kt * 64;
        __syncthreads();
        *(short8*)&Ks [sr * 40 + sc8] = kreg;
        *(short8*)&Ksl[sr * 40 + sc8] = kregl;
        *(short8*)&Vt [vd * 72 + vs8] = vreg;
        __syncthreads();
        if (kt < s1) {
            kreg  = *(const short8*)(Kg  + (size_t)(k0 + 64 + sr) * D3 + sc8);
            kregl = *(const short8*)(Klg + (size_t)(k0 + 64 + sr) * D3 + sc8);
            vreg  = *(const short8*)(Vg  + (size_t)vd * SS + k0 + 64 + vs8);
        }

        f32x4 s[4];
        #pragma unroll
        for (int cb = 0; cb < 4; cb++) {
            short8 kf  = *(const short8*)&Ks [(16 * cb + lm) * 40 + quad * 8];
            short8 kfl = *(const short8*)&Ksl[(16 * cb + lm) * 40 + quad * 8];
            f32x4 a = (f32x4){0.f, 0.f, 0.f, 0.f};
            a = __builtin_amdgcn_mfma_f32_16x16x32_bf16(ql, kf,  a, 0, 0, 0);
            a = __builtin_amdgcn_mfma_f32_16x16x32_bf16(qh, kfl, a, 0, 0, 0);
            a = __builtin_amdgcn_mfma_f32_16x16x32_bf16(qh, kf,  a, 0, 0, 0);
            s[cb] = a;
        }

        #pragma unroll
        for (int r = 0; r < 4; r++) {
            float s0r = s[0][r] * scl, s1r = s[1][r] * scl;
            float s2r = s[2][r] * scl, s3r = s[3][r] * scl;
            float tm = fmaxf(fmaxf(s0r, s1r), fmaxf(s2r, s3r));
            tm = fmaxf(tm, __shfl_xor(tm, 1, 64));
            tm = fmaxf(tm, __shfl_xor(tm, 2, 64));
            tm = fmaxf(tm, __shfl_xor(tm, 4, 64));
            tm = fmaxf(tm, __shfl_xor(tm, 8, 64));
            float mn = fmaxf(m[r], tm);
            float alpha = __expf(m[r] - mn);
            float p0 = __expf(s0r - mn), p1 = __expf(s1r - mn);
            float p2 = __expf(s2r - mn), p3 = __expf(s3r - mn);
            float ps = p0 + p1 + p2 + p3;
            ps += __shfl_xor(ps, 1, 64);
            ps += __shfl_xor(ps, 2, 64);
            ps += __shfl_xor(ps, 4, 64);
            ps += __shfl_xor(ps, 8, 64);
            l[r] = l[r] * alpha + ps;
            o[0][r] *= alpha;
            o[1][r] *= alpha;
            m[r] = mn;
            const int pr = (16 * wave + quad * 4 + r) * 72 + lm;
            Ps[pr +  0] = f2bfu(p0);
            Ps[pr + 16] = f2bfu(p1);
            Ps[pr + 32] = f2bfu(p2);
            Ps[pr + 48] = f2bfu(p3);
        }

        #pragma unroll
        for (int kc = 0; kc < 2; kc++) {
            short8 pf = *(const short8*)&Ps[(16 * wave + lm) * 72 + 32 * kc + quad * 8];
            #pragma unroll
            for (int nh = 0; nh < 2; nh++) {
                short8 vf = *(const short8*)&Vt[(16 * nh + lm) * 72 + 32 * kc + quad * 8];
                o[nh] = __builtin_amdgcn_mfma_f32_16x16x32_bf16(pf, vf, o[nh], 0, 0, 0);
            }
        }
    }

    #pragma unroll
    for (int r = 0; r < 4; r++) {
        int row = i0 + 16 * wave + quad * 4 + r;
        size_t base = ((size_t)seg * NTOK + b * SS + row) * DD + h * HD + lm;
        Of[base]      = o[0][r];
        Of[base + 16] = o[1][r];
        if (lm == 0)
            Ml[((size_t)seg * NTOK + b * SS + row) * HH + h] =
                make_float2(m[r], l[r]);
    }
}

// ---------------------------------------------------------------------------
// MFMA flash attention, FIXED-MAX softmax (post-LN inputs: scores O(1)).
// nseg==1: normalized bf16 out. nseg>1: f32 unnormalized partials + (32,l).
__global__ __launch_bounds__(256) void attn_fixed(
    const unsigned short* __restrict__ qkvh,
    const unsigned short* __restrict__ vth,
    unsigned short* __restrict__ outb,
    float* __restrict__ Of, float2* __restrict__ Ml,
    int win, int nseg)
{
    __shared__ __align__(16) unsigned short Ks[64 * 40];
    __shared__ __align__(16) unsigned short Vt[32 * 72];
    __shared__ __align__(16) unsigned short Ps[64 * 72];

    const int t = threadIdx.x;
    const int wave = t >> 6, lane = t & 63;
    const int lm = lane & 15, quad = lane >> 4;
    const int i0 = blockIdx.x * 64, h = blockIdx.y;
    const int z = blockIdx.z;
    const int b = z / nseg, seg = z - b * nseg;
    const int sr = t >> 2, sc8 = (t & 3) * 8;
    const int vd = t >> 3, vs8 = (t & 7) * 8;

    const size_t qoff = ((size_t)(b * SS) + i0 + 16 * wave + lm) * D3 + h * HD + quad * 8;
    short8 qh = *(const short8*)(qkvh + qoff);

    const unsigned short* Kg = qkvh + (size_t)(b * SS) * D3 + DD + h * HD;
    const unsigned short* Vg = vth + ((size_t)b * HH + h) * HD * SS;

    float l[4] = {0.f, 0.f, 0.f, 0.f};
    f32x4 o[2];
    o[0] = (f32x4){0.f, 0.f, 0.f, 0.f};
    o[1] = (f32x4){0.f, 0.f, 0.f, 0.f};

    int t0 = 0, t1 = SS / 64 - 1;
    const bool masked = (win < SS);
    if (masked) {
        t0 = (i0 - win) >> 6;        if (t0 < 0) t0 = 0;
        t1 = (i0 + 63 + win) >> 6;   if (t1 > SS / 64 - 1) t1 = SS / 64 - 1;
    }
    const int per = (t1 - t0 + nseg) / nseg;
    const int s0 = t0 + seg * per;
    const int s1 = (s0 + per - 1 < t1) ? (s0 + per - 1) : t1;
    const float scl = 0.17677669529663688f;  // 1/sqrt(32)
    const float M0 = 32.0f;                   // fixed softmax shift

    short8 kreg = *(const short8*)(Kg + (size_t)(s0 * 64 + sr) * D3 + sc8);
    short8 vreg = *(const short8*)(Vg + (size_t)vd * SS + s0 * 64 + vs8);

    for (int kt = s0; kt <= s1; kt++) {
        const int k0 = kt * 64;
        __syncthreads();
        *(short8*)&Ks[sr * 40 + sc8] = kreg;
        *(short8*)&Vt[vd * 72 + vs8] = vreg;
        __syncthreads();
        if (kt < s1) {
            kreg = *(const short8*)(Kg + (size_t)(k0 + 64 + sr) * D3 + sc8);
            vreg = *(const short8*)(Vg + (size_t)vd * SS + k0 + 64 + vs8);
        }

        f32x4 s[4];
        #pragma unroll
        for (int cb = 0; cb < 4; cb++) {
            short8 kf = *(const short8*)&Ks[(16 * cb + lm) * 40 + quad * 8];
            f32x4 a = (f32x4){0.f, 0.f, 0.f, 0.f};
            a = __builtin_amdgcn_mfma_f32_16x16x32_bf16(qh, kf, a, 0, 0, 0);
            s[cb] = a;
        }

        #pragma unroll
        for (int r = 0; r < 4; r++) {
            float p[4];
            #pragma unroll
            for (int cb = 0; cb < 4; cb++) {
                float v = s[cb][r] * scl;
                if (masked) {
                    int di = (i0 + 16 * wave + quad * 4 + r) - (k0 + 16 * cb + lm);
                    if (di > win || di < -win) v = -1e30f;
                }
                p[cb] = __expf(v - M0);
            }
            l[r] += p[0] + p[1] + p[2] + p[3];
            const int pr = (16 * wave + quad * 4 + r) * 72 + lm;
            Ps[pr +  0] = f2bfu(p[0]);
            Ps[pr + 16] = f2bfu(p[1]);
            Ps[pr + 32] = f2bfu(p[2]);
            Ps[pr + 48] = f2bfu(p[3]);
        }
        // Ps region is wave-private — no barrier needed

        #pragma unroll
        for (int kc = 0; kc < 2; kc++) {
            short8 pf = *(const short8*)&Ps[(16 * wave + lm) * 72 + 32 * kc + quad * 8];
            #pragma unroll
            for (int nh = 0; nh < 2; nh++) {
                short8 vf = *(const short8*)&Vt[(16 * nh + lm) * 72 + 32 * kc + quad * 8];
                o[nh] = __builtin_amdgcn_mfma_f32_16x16x32_bf16(pf, vf, o[nh], 0, 0, 0);
            }
        }
    }

    #pragma unroll
    for (int r = 0; r < 4; r++) {
        l[r] += __shfl_xor(l[r], 1, 64);
        l[r] += __shfl_xor(l[r], 2, 64);
        l[r] += __shfl_xor(l[r], 4, 64);
        l[r] += __shfl_xor(l[r], 8, 64);
    }

    if (nseg == 1) {
        #pragma unroll
        for (int r = 0; r < 4; r++) {
            float invl = 1.0f / l[r];
            size_t base = ((size_t)(b * SS) + i0 + 16 * wave + quad * 4 + r) * DD + h * HD + lm;
            outb[base]      = f2bfu(o[0][r] * invl);
            outb[base + 16] = f2bfu(o[1][r] * invl);
        }
    } else {
        #pragma unroll
        for (int r = 0; r < 4; r++) {
            int row = i0 + 16 * wave + quad * 4 + r;
            size_t base = ((size_t)seg * NTOK + b * SS + row) * DD + h * HD + lm;
            Of[base]      = o[0][r];
            Of[base + 16] = o[1][r];
            if (lm == 0)
                Ml[((size_t)seg * NTOK + b * SS + row) * HH + h] =
                    make_float2(M0, l[r]);
        }
    }
}

// ---------------------------------------------------------------------------
extern "C" void kernel_launch(void* const* d_in, const int* in_sizes, int n_in,
                              void* d_out, int out_size, void* d_ws, size_t ws_size,
                              hipStream_t stream)
{
    const float* xin   = (const float*)d_in[0];
    const float* scale = (const float*)d_in[1];
    const float* Win_a = (const float*)d_in[2];
    const float* bin_a = (const float*)d_in[3];
    const float* Wout_a= (const float*)d_in[4];
    const float* bout_a= (const float*)d_in[5];
    const float* Win_e = (const float*)d_in[6];
    const float* bin_e = (const float*)d_in[7];
    const float* Wout_e= (const float*)d_in[8];
    const float* bout_e= (const float*)d_in[9];
    const float* ln1_g = (const float*)d_in[10];
    const float* ln1_b = (const float*)d_in[11];
    const float* ln2_g = (const float*)d_in[12];
    const float* ln2_b = (const float*)d_in[13];
    const float* W1    = (const float*)d_in[14];
    const float* b1    = (const float*)d_in[15];
    const float* W2    = (const float*)d_in[16];
    const float* b2    = (const float*)d_in[17];
    const float* lnf_g = (const float*)d_in[18];
    const float* lnf_b = (const float*)d_in[19];

    char* ws = (char*)d_ws;
    float* X    = (float*)ws;                     ws += (size_t)NTOK * DD * 4;
    float* X2   = (float*)ws;                     ws += (size_t)NTOK * DD * 4;
    unsigned short* Xb   = (unsigned short*)ws;   ws += (size_t)NTOK * DD * 2;
    unsigned short* Xlb  = (unsigned short*)ws;   ws += (size_t)NTOK * DD * 2;
    unsigned short* X2b  = (unsigned short*)ws;   ws += (size_t)NTOK * DD * 2;
    unsigned short* ATb  = (unsigned short*)ws;   ws += (size_t)NTOK * DD * 2;
    unsigned short* QKVb = (unsigned short*)ws;   ws += (size_t)NTOK * D3 * 2;
    unsigned short* QKVl = (unsigned short*)ws;   ws += (size_t)NTOK * D3 * 2;
    unsigned short* VTh  = (unsigned short*)ws;   ws += (size_t)NTOK * DD * 2;
    unsigned short* HMLb = (unsigned short*)ws;   ws += (size_t)NTOK * MLP * 2;
    unsigned short* Wb   = (unsigned short*)ws;   ws += (size_t)W_TOT * 2;
    unsigned short* Wl0  = (unsigned short*)ws;   ws += (size_t)WL0 * 2;
    float2* Ml           = (float2*)ws;           ws += (size_t)NSEG * NTOK * HH * 8;
    float* Of            = (float*)ws;            ws += (size_t)NSEG * NTOK * DD * 4;

    unsigned short* WinA_b  = Wb + 0;
    unsigned short* WoutA_b = Wb + 393216;
    unsigned short* WinE_b  = Wb + 524288;
    unsigned short* WoutE_b = Wb + 917504;
    unsigned short* W1_b    = Wb + 1048576;
    unsigned short* W2_b    = Wb + 1572864;

    prep_kernel<<<WBLK + PBLK, 256, 0, stream>>>(
        Win_a, Wout_a, Win_e, Wout_e, W1, W2, Wb, Wl0,
        xin, scale, X, Xb, Xlb);

    float* cur = X;            float* oth = X2;
    unsigned short* curb = Xb; unsigned short* othb = X2b;

    for (int l = 0; l < 2; l++) {
        // --- full self-attention (split-K NSEG, combine+LN fused into Wout)
        if (l == 0) {
            gemm_mfma_split<<<dim3(D3 / 128, NTOK / 64), 256, 0, stream>>>(
                Xb, Xlb, WinA_b, Wl0, bin_a, QKVb, QKVl, VTh, NTOK, D3, DD);
            attn_split<<<dim3(SS / 64, HH, BB * NSEG), 256, 0, stream>>>(
                QKVb, QKVl, VTh, Of, Ml);
        } else {
            gemm_mfma<<<dim3(D3 / 128, NTOK / 64), 256, 0, stream>>>(
                curb, WinA_b + (size_t)l * D3 * DD, bin_a + (size_t)l * D3,
                nullptr, nullptr, QKVb, VTh, NTOK, D3, DD, 0);
            attn_fixed<<<dim3(SS / 64, HH, BB * NSEG), 256, 0, stream>>>(
                QKVb, VTh, nullptr, Of, Ml, 1 << 28, NSEG);
        }
        gemm_ln<true><<<NTOK / 16, 256, 0, stream>>>(
            nullptr, Of, Ml, WoutA_b + (size_t)l * DD * DD,
            bout_a + (size_t)l * DD, cur,
            ln1_g + l * DD, ln1_b + l * DD, oth, othb, DD);

        // --- banded self-attention (|i-j| <= 64), LN fused into Wout
        gemm_mfma<<<dim3(D3 / 128, NTOK / 64), 256, 0, stream>>>(
            othb, WinE_b + (size_t)l * D3 * DD, bin_e + (size_t)l * D3,
            nullptr, nullptr, QKVb, VTh, NTOK, D3, DD, 0);
        attn_fixed<<<dim3(SS / 64, HH, BB), 256, 0, stream>>>(
            QKVb, VTh, ATb, nullptr, nullptr, 64, 1);
        gemm_ln<false><<<NTOK / 16, 256, 0, stream>>>(
            ATb, nullptr, nullptr, WoutE_b + (size_t)l * DD * DD,
            bout_e + (size_t)l * DD, oth,
            ln2_g + l * DD, ln2_b + l * DD, cur, curb, DD);
        // attended now in cur/curb

        // --- MLP with exact gelu; layer-1's W2 fuses the final LayerNorm
        gemm_mfma<<<dim3(MLP / 128, NTOK / 64), 256, 0, stream>>>(
            curb, W1_b + (size_t)l * MLP * DD, b1 + (size_t)l * MLP,
            nullptr, nullptr, HMLb, nullptr, NTOK, MLP, DD, 1);
        if (l == 0) {
            gemm_mfma<<<dim3(DD / 128, NTOK / 64), 256, 0, stream>>>(
                HMLb, W2_b + (size_t)l * DD * MLP, b2 + (size_t)l * DD,
                cur, oth, othb, nullptr, NTOK, DD, MLP, 0);
            float* tf = cur; cur = oth; oth = tf;
            unsigned short* tb = curb; curb = othb; othb = tb;
        } else {
            gemm_ln<false><<<NTOK / 16, 256, 0, stream>>>(
                HMLb, nullptr, nullptr, W2_b + (size_t)l * DD * MLP,
                b2 + (size_t)l * DD, cur,
                lnf_g, lnf_b, (float*)d_out, nullptr, MLP);
        }
    }
}

// Round 17
// 328.066 us; speedup vs baseline: 5.6813x; 1.0196x over previous
//
#include <hip/hip_runtime.h>
#include <math.h>

// Problem constants
#define BB 4
#define SS 1024
#define DD 256
#define HH 8
#define HD 32
#define D3 768
#define MLP 1024
#define NTOK (BB * SS)   // 4096
#define NSEG 4           // split-K segments for full attention

typedef __attribute__((ext_vector_type(8))) short short8;
typedef __attribute__((ext_vector_type(4))) float f32x4;

__device__ __forceinline__ unsigned short f2bfu(float f) {
    union { float f; unsigned i; } u; u.f = f;
    unsigned r = u.i + 0x7fffu + ((u.i >> 16) & 1u);   // RNE
    return (unsigned short)(r >> 16);
}
__device__ __forceinline__ float bfu2f(unsigned short h) {
    union { unsigned i; float f; } u; u.i = ((unsigned)h) << 16; return u.f;
}

// ---------------------------------------------------------------------------
// Fused prep: weights fp32->bf16 (+lo for Win_a layer 0)  AND  x+pos encode.
#define W_TOT 2097152
#define WL0   196608   // 768*256 = Win_a layer 0
#define WBLK  (W_TOT / 256)          // 8192 weight blocks
#define PBLK  (NTOK * DD / 256)      // 4096 pos blocks
__global__ __launch_bounds__(256) void prep_kernel(
    const float* __restrict__ a0, const float* __restrict__ a1,
    const float* __restrict__ a2, const float* __restrict__ a3,
    const float* __restrict__ a4, const float* __restrict__ a5,
    unsigned short* __restrict__ out, unsigned short* __restrict__ out_lo,
    const float* __restrict__ x, const float* __restrict__ scale,
    float* __restrict__ xf, unsigned short* __restrict__ xh,
    unsigned short* __restrict__ xl)
{
    if (blockIdx.x < WBLK) {
        int i = blockIdx.x * 256 + threadIdx.x;
        const float* s; int off;
        if      (i <  393216) { s = a0; off = 0;       }
        else if (i <  524288) { s = a1; off = 393216;  }
        else if (i <  917504) { s = a2; off = 524288;  }
        else if (i < 1048576) { s = a3; off = 917504;  }
        else if (i < 1572864) { s = a4; off = 1048576; }
        else                  { s = a5; off = 1572864; }
        float v = s[i - off];
        unsigned short h = f2bfu(v);
        out[i] = h;
        if (i < WL0) out_lo[i] = f2bfu(v - bfu2f(h));
    } else {
        int i = (blockIdx.x - WBLK) * 256 + threadIdx.x;
        int s = (i >> 8) & (SS - 1);
        float v = x[i] + (float)s * scale[0];
        xf[i] = v;
        unsigned short h = f2bfu(v);
        xh[i] = h;
        xl[i] = f2bfu(v - bfu2f(h));
    }
}

// ---------------------------------------------------------------------------
// V-epilogue helper: token row + V-column -> VT[b][h][d][s] index
__device__ __forceinline__ size_t vt_index(int row, int col512) {
    int b = row >> 10, s = row & (SS - 1);
    int h = col512 >> 5, d = col512 & (HD - 1);
    return (((size_t)b * HH + h) * HD + d) * SS + s;
}

// ---------------------------------------------------------------------------
// MFMA GEMM: C[M,N] = A[M,K](bf16) @ W[N,K]^T(bf16) + bias(f32)
//            [+gelu] [+resid f32] -> outf (f32) and/or outb (bf16)
// If vth != null (QKV proj): cols >= 512 go transposed to VT[b][h][d][s].
// 64x128 block tile, 256 thr = 4 waves (2x2 of 32x64), BK=32, reg prefetch.
#define LDP 40
__global__ __launch_bounds__(256) void gemm_mfma(
    const unsigned short* __restrict__ A, const unsigned short* __restrict__ W,
    const float* __restrict__ bias, const float* __restrict__ resid,
    float* __restrict__ outf, unsigned short* __restrict__ outb,
    unsigned short* __restrict__ vth,
    int M, int N, int K, int act)
{
    __shared__ __align__(16) unsigned short As[64 * LDP];
    __shared__ __align__(16) unsigned short Bs[128 * LDP];
    const int t = threadIdx.x;
    const int lane = t & 63, wave = t >> 6;
    const int wr = wave >> 1, wc = wave & 1;
    const int m0 = blockIdx.y * 64, n0 = blockIdx.x * 128;
    const int sr = t >> 2;
    const int sc = (t & 3) * 8;

    const unsigned short* Ag = A + (size_t)(m0 + sr) * K + sc;
    const unsigned short* Wg = W + (size_t)(n0 + sr) * K + sc;

    f32x4 acc[2][4];
    #pragma unroll
    for (int i = 0; i < 2; i++)
        #pragma unroll
        for (int j = 0; j < 4; j++)
            acc[i][j] = (f32x4){0.f, 0.f, 0.f, 0.f};

    const int lm = lane & 15, lk = (lane >> 4) * 8;

    uint4 a0 = *(const uint4*)(Ag);
    uint4 b0 = *(const uint4*)(Wg);
    uint4 b1 = *(const uint4*)(Wg + (size_t)64 * K);

    for (int k0 = 0; k0 < K; k0 += 32) {
        __syncthreads();
        *(uint4*)&As[sr * LDP + sc]        = a0;
        *(uint4*)&Bs[sr * LDP + sc]        = b0;
        *(uint4*)&Bs[(sr + 64) * LDP + sc] = b1;
        __syncthreads();
        if (k0 + 32 < K) {
            a0 = *(const uint4*)(Ag + k0 + 32);
            b0 = *(const uint4*)(Wg + k0 + 32);
            b1 = *(const uint4*)(Wg + (size_t)64 * K + k0 + 32);
        }

        short8 af[2], bf[4];
        #pragma unroll
        for (int i = 0; i < 2; i++)
            af[i] = *(const short8*)&As[(wr * 32 + i * 16 + lm) * LDP + lk];
        #pragma unroll
        for (int j = 0; j < 4; j++)
            bf[j] = *(const short8*)&Bs[(wc * 64 + j * 16 + lm) * LDP + lk];
        #pragma unroll
        for (int i = 0; i < 2; i++)
            #pragma unroll
            for (int j = 0; j < 4; j++)
                acc[i][j] = __builtin_amdgcn_mfma_f32_16x16x32_bf16(
                    af[i], bf[j], acc[i][j], 0, 0, 0);
    }

    const int lq = lane >> 4;
    #pragma unroll
    for (int j = 0; j < 4; j++) {
        int col = n0 + wc * 64 + j * 16 + lm;
        float bv = bias[col];
        #pragma unroll
        for (int i = 0; i < 2; i++) {
            #pragma unroll
            for (int r = 0; r < 4; r++) {
                int row = m0 + wr * 32 + i * 16 + lq * 4 + r;
                float v = acc[i][j][r] + bv;
                if (act) v = 0.5f * v * (1.0f + erff(v * 0.70710678118654752f));
                if (vth && col >= 2 * DD) {
                    vth[vt_index(row, col - 2 * DD)] = f2bfu(v);
                } else {
                    size_t idx = (size_t)row * N + col;
                    if (resid) v += resid[idx];
                    if (outf) outf[idx] = v;
                    if (outb) outb[idx] = f2bfu(v);
                }
            }
        }
    }
}

// ---------------------------------------------------------------------------
// Full-row GEMM (N=256) + residual [+ LayerNorm] fused epilogue.
// COMBINE: A built from split-K attention partials (Of, Ml) with softmax
// combine+normalize in the staging path; else A is plain bf16.
// DOLN: apply per-row LayerNorm; else write bias+resid directly.
// 16x256 block tile (grid NTOK/16 = 256 blocks — full machine), 4 waves
// each computing 16x64, BK=32.
template<bool COMBINE, bool DOLN>
__global__ __launch_bounds__(256) void gemm_ln(
    const unsigned short* __restrict__ A,
    const float* __restrict__ Of, const float2* __restrict__ Ml,
    const unsigned short* __restrict__ W, const float* __restrict__ bias,
    const float* __restrict__ resid,
    const float* __restrict__ g, const float* __restrict__ bt,
    float* __restrict__ outf, unsigned short* __restrict__ outb, int K)
{
    __shared__ __align__(16) unsigned short As[16 * LDP];    // 1.3 KB
    __shared__ __align__(16) unsigned short Bs[256 * LDP];   // 20.5 KB
    __shared__ float rsum[4][16];
    __shared__ float rsum2[4][16];
    const int t = threadIdx.x;
    const int lane = t & 63, wave = t >> 6;
    const int m0 = blockIdx.x * 16;
    const int sr = t >> 2;          // 0..63 (B staging rows, x4 strided)
    const int sc = (t & 3) * 8;
    const int arow = t >> 2;        // A staging uses t<64: rows 0..15
    const int acol = (t & 3) * 8;

    const unsigned short* Wg = W + (size_t)sr * K + sc;

    f32x4 acc[4];
    #pragma unroll
    for (int j = 0; j < 4; j++) acc[j] = (f32x4){0.f, 0.f, 0.f, 0.f};

    const int lm = lane & 15, lk = (lane >> 4) * 8;
    const int quad = lane >> 4;

    for (int k0 = 0; k0 < K; k0 += 32) {
        unsigned short ab[8];
        const bool aload = (t < 64);
        if (aload) {
            const int token = m0 + arow;
            if (COMBINE) {
                const int h = (k0 + acol) >> 5;
                float2 ml[NSEG];
                float M = -1e30f;
                #pragma unroll
                for (int s = 0; s < NSEG; s++) {
                    ml[s] = Ml[((size_t)s * NTOK + token) * HH + h];
                    M = fmaxf(M, ml[s].x);
                }
                float wgt[NSEG]; float denom = 0.f;
                #pragma unroll
                for (int s = 0; s < NSEG; s++) {
                    wgt[s] = __expf(ml[s].x - M);
                    denom += ml[s].y * wgt[s];
                }
                const float inv = 1.0f / denom;
                float a8[8] = {};
                #pragma unroll
                for (int s = 0; s < NSEG; s++) {
                    const float* p = Of + ((size_t)s * NTOK + token) * DD + k0 + acol;
                    float4 x0 = *(const float4*)p;
                    float4 x1 = *(const float4*)(p + 4);
                    a8[0] += x0.x * wgt[s]; a8[1] += x0.y * wgt[s];
                    a8[2] += x0.z * wgt[s]; a8[3] += x0.w * wgt[s];
                    a8[4] += x1.x * wgt[s]; a8[5] += x1.y * wgt[s];
                    a8[6] += x1.z * wgt[s]; a8[7] += x1.w * wgt[s];
                }
                #pragma unroll
                for (int c = 0; c < 8; c++) ab[c] = f2bfu(a8[c] * inv);
            } else {
                uint4 av = *(const uint4*)(A + (size_t)(m0 + arow) * K + k0 + acol);
                *(uint4*)ab = av;
            }
        }
        uint4 b0 = *(const uint4*)(Wg + k0);
        uint4 b1 = *(const uint4*)(Wg + (size_t)64 * K + k0);
        uint4 b2 = *(const uint4*)(Wg + (size_t)128 * K + k0);
        uint4 b3 = *(const uint4*)(Wg + (size_t)192 * K + k0);
        __syncthreads();
        if (aload) *(uint4*)&As[arow * LDP + acol] = *(uint4*)ab;
        *(uint4*)&Bs[sr * LDP + sc]         = b0;
        *(uint4*)&Bs[(sr + 64) * LDP + sc]  = b1;
        *(uint4*)&Bs[(sr + 128) * LDP + sc] = b2;
        *(uint4*)&Bs[(sr + 192) * LDP + sc] = b3;
        __syncthreads();

        short8 af = *(const short8*)&As[lm * LDP + lk];
        #pragma unroll
        for (int j = 0; j < 4; j++) {
            short8 bf = *(const short8*)&Bs[(wave * 64 + j * 16 + lm) * LDP + lk];
            acc[j] = __builtin_amdgcn_mfma_f32_16x16x32_bf16(af, bf, acc[j], 0, 0, 0);
        }
    }

    // ---- epilogue: bias + resid [+ per-row LayerNorm].
    // Wave w holds rows (quad*4+r) x cols (64w + 16j + lm).
    #pragma unroll
    for (int j = 0; j < 4; j++) {
        int col = wave * 64 + j * 16 + lm;
        float bv = bias[col];
        #pragma unroll
        for (int r = 0; r < 4; r++) {
            int row = m0 + quad * 4 + r;
            acc[j][r] += bv + resid[(size_t)row * DD + col];
        }
    }
    if (!DOLN) {
        #pragma unroll
        for (int j = 0; j < 4; j++) {
            int col = wave * 64 + j * 16 + lm;
            #pragma unroll
            for (int r = 0; r < 4; r++) {
                int row = m0 + quad * 4 + r;
                size_t idx = (size_t)row * DD + col;
                if (outf) outf[idx] = acc[j][r];
                if (outb) outb[idx] = f2bfu(acc[j][r]);
            }
        }
        return;
    }
    #pragma unroll
    for (int r = 0; r < 4; r++) {
        float s = 0.f;
        #pragma unroll
        for (int j = 0; j < 4; j++) s += acc[j][r];
        s += __shfl_xor(s, 1, 64); s += __shfl_xor(s, 2, 64);
        s += __shfl_xor(s, 4, 64); s += __shfl_xor(s, 8, 64);
        if (lm == 0) rsum[wave][quad * 4 + r] = s;
    }
    __syncthreads();
    float mean_[4];
    #pragma unroll
    for (int r = 0; r < 4; r++) {
        int ri = quad * 4 + r;
        mean_[r] = (rsum[0][ri] + rsum[1][ri] + rsum[2][ri] + rsum[3][ri])
                 * (1.0f / 256.0f);
    }
    #pragma unroll
    for (int r = 0; r < 4; r++) {
        float s2 = 0.f;
        #pragma unroll
        for (int j = 0; j < 4; j++) {
            float d = acc[j][r] - mean_[r];
            s2 += d * d;
        }
        s2 += __shfl_xor(s2, 1, 64); s2 += __shfl_xor(s2, 2, 64);
        s2 += __shfl_xor(s2, 4, 64); s2 += __shfl_xor(s2, 8, 64);
        if (lm == 0) rsum2[wave][quad * 4 + r] = s2;
    }
    __syncthreads();
    float rstd[4];
    #pragma unroll
    for (int r = 0; r < 4; r++) {
        int ri = quad * 4 + r;
        rstd[r] = rsqrtf((rsum2[0][ri] + rsum2[1][ri] + rsum2[2][ri] + rsum2[3][ri])
                         * (1.0f / 256.0f) + 1e-5f);
    }
    #pragma unroll
    for (int j = 0; j < 4; j++) {
        int col = wave * 64 + j * 16 + lm;
        float gv = g[col], bv2 = bt[col];
        #pragma unroll
        for (int r = 0; r < 4; r++) {
            int row = m0 + quad * 4 + r;
            float ov = (acc[j][r] - mean_[r]) * rstd[r] * gv + bv2;
            size_t idx = (size_t)row * DD + col;
            if (outf) outf[idx] = ov;
            if (outb) outb[idx] = f2bfu(ov);
        }
    }
}

// ---------------------------------------------------------------------------
// Split (hi/lo bf16 ~ fp32) MFMA GEMM for the layer-0 QKV projection.
// Q,K -> packed hi/lo; V -> transposed VT (hi only). Register-prefetched.
__global__ __launch_bounds__(256) void gemm_mfma_split(
    const unsigned short* __restrict__ Ah, const unsigned short* __restrict__ Al,
    const unsigned short* __restrict__ Wh, const unsigned short* __restrict__ Wl,
    const float* __restrict__ bias,
    unsigned short* __restrict__ outh, unsigned short* __restrict__ outl,
    unsigned short* __restrict__ vth,
    int M, int N, int K)
{
    __shared__ __align__(16) unsigned short Ash[64 * LDP];
    __shared__ __align__(16) unsigned short Asl[64 * LDP];
    __shared__ __align__(16) unsigned short Bsh[128 * LDP];
    __shared__ __align__(16) unsigned short Bsl[128 * LDP];
    const int t = threadIdx.x;
    const int lane = t & 63, wave = t >> 6;
    const int wr = wave >> 1, wc = wave & 1;
    const int m0 = blockIdx.y * 64, n0 = blockIdx.x * 128;
    const int sr = t >> 2;
    const int sc = (t & 3) * 8;

    const size_t oA = (size_t)(m0 + sr) * K + sc;
    const size_t oW = (size_t)(n0 + sr) * K + sc;

    f32x4 acc[2][4];
    #pragma unroll
    for (int i = 0; i < 2; i++)
        #pragma unroll
        for (int j = 0; j < 4; j++)
            acc[i][j] = (f32x4){0.f, 0.f, 0.f, 0.f};

    const int lm = lane & 15, lk = (lane >> 4) * 8;

    uint4 ah0 = *(const uint4*)(Ah + oA);
    uint4 al0 = *(const uint4*)(Al + oA);
    uint4 bh0 = *(const uint4*)(Wh + oW);
    uint4 bh1 = *(const uint4*)(Wh + oW + (size_t)64 * K);
    uint4 bl0 = *(const uint4*)(Wl + oW);
    uint4 bl1 = *(const uint4*)(Wl + oW + (size_t)64 * K);

    for (int k0 = 0; k0 < K; k0 += 32) {
        __syncthreads();
        *(uint4*)&Ash[sr * LDP + sc]        = ah0;
        *(uint4*)&Asl[sr * LDP + sc]        = al0;
        *(uint4*)&Bsh[sr * LDP + sc]        = bh0;
        *(uint4*)&Bsh[(sr + 64) * LDP + sc] = bh1;
        *(uint4*)&Bsl[sr * LDP + sc]        = bl0;
        *(uint4*)&Bsl[(sr + 64) * LDP + sc] = bl1;
        __syncthreads();
        if (k0 + 32 < K) {
            ah0 = *(const uint4*)(Ah + oA + k0 + 32);
            al0 = *(const uint4*)(Al + oA + k0 + 32);
            bh0 = *(const uint4*)(Wh + oW + k0 + 32);
            bh1 = *(const uint4*)(Wh + oW + (size_t)64 * K + k0 + 32);
            bl0 = *(const uint4*)(Wl + oW + k0 + 32);
            bl1 = *(const uint4*)(Wl + oW + (size_t)64 * K + k0 + 32);
        }

        short8 afh[2], afl[2], bfh[4], bfl[4];
        #pragma unroll
        for (int i = 0; i < 2; i++) {
            afh[i] = *(const short8*)&Ash[(wr * 32 + i * 16 + lm) * LDP + lk];
            afl[i] = *(const short8*)&Asl[(wr * 32 + i * 16 + lm) * LDP + lk];
        }
        #pragma unroll
        for (int j = 0; j < 4; j++) {
            bfh[j] = *(const short8*)&Bsh[(wc * 64 + j * 16 + lm) * LDP + lk];
            bfl[j] = *(const short8*)&Bsl[(wc * 64 + j * 16 + lm) * LDP + lk];
        }
        #pragma unroll
        for (int i = 0; i < 2; i++)
            #pragma unroll
            for (int j = 0; j < 4; j++) {
                acc[i][j] = __builtin_amdgcn_mfma_f32_16x16x32_bf16(
                    afl[i], bfh[j], acc[i][j], 0, 0, 0);
                acc[i][j] = __builtin_amdgcn_mfma_f32_16x16x32_bf16(
                    afh[i], bfl[j], acc[i][j], 0, 0, 0);
                acc[i][j] = __builtin_amdgcn_mfma_f32_16x16x32_bf16(
                    afh[i], bfh[j], acc[i][j], 0, 0, 0);
            }
    }

    const int lq = lane >> 4;
    #pragma unroll
    for (int j = 0; j < 4; j++) {
        int col = n0 + wc * 64 + j * 16 + lm;
        float bv = bias[col];
        #pragma unroll
        for (int i = 0; i < 2; i++) {
            #pragma unroll
            for (int r = 0; r < 4; r++) {
                int row = m0 + wr * 32 + i * 16 + lq * 4 + r;
                float v = acc[i][j][r] + bv;
                unsigned short h = f2bfu(v);
                if (col >= 2 * DD) {
                    vth[vt_index(row, col - 2 * DD)] = h;
                } else {
                    size_t idx = (size_t)row * N + col;
                    outh[idx] = h;
                    outl[idx] = f2bfu(v - bfu2f(h));
                }
            }
        }
    }
}

// ---------------------------------------------------------------------------
// MFMA flash attention, SPLIT (hi/lo) scores with ONLINE softmax — layer-0
// full attention only. V hi-only (lo term <= bf16-rounding of O). Split-K.
__global__ __launch_bounds__(256) void attn_split(
    const unsigned short* __restrict__ qkvh,
    const unsigned short* __restrict__ qkvl,
    const unsigned short* __restrict__ vth,
    float* __restrict__ Of, float2* __restrict__ Ml)
{
    __shared__ __align__(16) unsigned short Ks [64 * 40];
    __shared__ __align__(16) unsigned short Vt [32 * 72];
    __shared__ __align__(16) unsigned short Ps [64 * 72];
    __shared__ __align__(16) unsigned short Ksl[64 * 40];

    const int t = threadIdx.x;
    const int wave = t >> 6, lane = t & 63;
    const int lm = lane & 15, quad = lane >> 4;
    const int i0 = blockIdx.x * 64, h = blockIdx.y;
    const int z = blockIdx.z;
    const int b = z >> 2, seg = z & (NSEG - 1);
    const int sr = t >> 2, sc8 = (t & 3) * 8;
    const int vd = t >> 3, vs8 = (t & 7) * 8;

    const size_t qoff = ((size_t)(b * SS) + i0 + 16 * wave + lm) * D3 + h * HD + quad * 8;
    short8 qh = *(const short8*)(qkvh + qoff);
    short8 ql = *(const short8*)(qkvl + qoff);

    const unsigned short* Kg  = qkvh + (size_t)(b * SS) * D3 + DD + h * HD;
    const unsigned short* Klg = qkvl + (size_t)(b * SS) * D3 + DD + h * HD;
    const unsigned short* Vg  = vth + ((size_t)b * HH + h) * HD * SS;

    float m[4], l[4];
    f32x4 o[2];
    #pragma unroll
    for (int r = 0; r < 4; r++) { m[r] = -1e30f; l[r] = 0.f; }
    o[0] = (f32x4){0.f, 0.f, 0.f, 0.f};
    o[1] = (f32x4){0.f, 0.f, 0.f, 0.f};

    const int per = (SS / 64) / NSEG;
    const int s0 = seg * per, s1 = s0 + per - 1;
    const float scl = 0.17677669529663688f;  // 1/sqrt(32)

    short8 kreg  = *(const short8*)(Kg  + (size_t)(s0 * 64 + sr) * D3 + sc8);
    short8 kregl = *(const short8*)(Klg + (size_t)(s0 * 64 + sr) * D3 + sc8);
    short8 vreg  = *(const short8*)(Vg  + (size_t)vd * SS + s0 * 64 + vs8);

    for (int kt = s0; kt <= s1; kt++) {
        const int k0 = kt * 64;
        __syncthreads();
        *(short8*)&Ks [sr * 40 + sc8] = kreg;
        *(short8*)&Ksl[sr * 40 + sc8] = kregl;
        *(short8*)&Vt [vd * 72 + vs8] = vreg;
        __syncthreads();
        if (kt < s1) {
            kreg  = *(const short8*)(Kg  + (size_t)(k0 + 64 + sr) * D3 + sc8);
            kregl = *(const short8*)(Klg + (size_t)(k0 + 64 + sr) * D3 + sc8);
            vreg  = *(const short8*)(Vg  + (size_t)vd * SS + k0 + 64 + vs8);
        }

        f32x4 s[4];
        #pragma unroll
        for (int cb = 0; cb < 4; cb++) {
            short8 kf  = *(const short8*)&Ks [(16 * cb + lm) * 40 + quad * 8];
            short8 kfl = *(const short8*)&Ksl[(16 * cb + lm) * 40 + quad * 8];
            f32x4 a = (f32x4){0.f, 0.f, 0.f, 0.f};
            a = __builtin_amdgcn_mfma_f32_16x16x32_bf16(ql, kf,  a, 0, 0, 0);
            a = __builtin_amdgcn_mfma_f32_16x16x32_bf16(qh, kfl, a, 0, 0, 0);
            a = __builtin_amdgcn_mfma_f32_16x16x32_bf16(qh, kf,  a, 0, 0, 0);
            s[cb] = a;
        }

        #pragma unroll
        for (int r = 0; r < 4; r++) {
            float s0r = s[0][r] * scl, s1r = s[1][r] * scl;
            float s2r = s[2][r] * scl, s3r = s[3][r] * scl;
            float tm = fmaxf(fmaxf(s0r, s1r), fmaxf(s2r, s3r));
            tm = fmaxf(tm, __shfl_xor(tm, 1, 64));
            tm = fmaxf(tm, __shfl_xor(tm, 2, 64));
            tm = fmaxf(tm, __shfl_xor(tm, 4, 64));
            tm = fmaxf(tm, __shfl_xor(tm, 8, 64));
            float mn = fmaxf(m[r], tm);
            float alpha = __expf(m[r] - mn);
            float p0 = __expf(s0r - mn), p1 = __expf(s1r - mn);
            float p2 = __expf(s2r - mn), p3 = __expf(s3r - mn);
            float ps = p0 + p1 + p2 + p3;
            ps += __shfl_xor(ps, 1, 64);
            ps += __shfl_xor(ps, 2, 64);
            ps += __shfl_xor(ps, 4, 64);
            ps += __shfl_xor(ps, 8, 64);
            l[r] = l[r] * alpha + ps;
            o[0][r] *= alpha;
            o[1][r] *= alpha;
            m[r] = mn;
            const int pr = (16 * wave + quad * 4 + r) * 72 + lm;
            Ps[pr +  0] = f2bfu(p0);
            Ps[pr + 16] = f2bfu(p1);
            Ps[pr + 32] = f2bfu(p2);
            Ps[pr + 48] = f2bfu(p3);
        }

        #pragma unroll
        for (int kc = 0; kc < 2; kc++) {
            short8 pf = *(const short8*)&Ps[(16 * wave + lm) * 72 + 32 * kc + quad * 8];
            #pragma unroll
            for (int nh = 0; nh < 2; nh++) {
                short8 vf = *(const short8*)&Vt[(16 * nh + lm) * 72 + 32 * kc + quad * 8];
                o[nh] = __builtin_amdgcn_mfma_f32_16x16x32_bf16(pf, vf, o[nh], 0, 0, 0);
            }
        }
    }

    #pragma unroll
    for (int r = 0; r < 4; r++) {
        int row = i0 + 16 * wave + quad * 4 + r;
        size_t base = ((size_t)seg * NTOK + b * SS + row) * DD + h * HD + lm;
        Of[base]      = o[0][r];
        Of[base + 16] = o[1][r];
        if (lm == 0)
            Ml[((size_t)seg * NTOK + b * SS + row) * HH + h] =
                make_float2(m[r], l[r]);
    }
}

// ---------------------------------------------------------------------------
// MFMA flash attention, FIXED-MAX softmax (post-LN inputs: scores O(1)).
// nseg==1: normalized bf16 out. nseg>1: f32 unnormalized partials + (32,l).
__global__ __launch_bounds__(256) void attn_fixed(
    const unsigned short* __restrict__ qkvh,
    const unsigned short* __restrict__ vth,
    unsigned short* __restrict__ outb,
    float* __restrict__ Of, float2* __restrict__ Ml,
    int win, int nseg)
{
    __shared__ __align__(16) unsigned short Ks[64 * 40];
    __shared__ __align__(16) unsigned short Vt[32 * 72];
    __shared__ __align__(16) unsigned short Ps[64 * 72];

    const int t = threadIdx.x;
    const int wave = t >> 6, lane = t & 63;
    const int lm = lane & 15, quad = lane >> 4;
    const int i0 = blockIdx.x * 64, h = blockIdx.y;
    const int z = blockIdx.z;
    const int b = z / nseg, seg = z - b * nseg;
    const int sr = t >> 2, sc8 = (t & 3) * 8;
    const int vd = t >> 3, vs8 = (t & 7) * 8;

    const size_t qoff = ((size_t)(b * SS) + i0 + 16 * wave + lm) * D3 + h * HD + quad * 8;
    short8 qh = *(const short8*)(qkvh + qoff);

    const unsigned short* Kg = qkvh + (size_t)(b * SS) * D3 + DD + h * HD;
    const unsigned short* Vg = vth + ((size_t)b * HH + h) * HD * SS;

    float l[4] = {0.f, 0.f, 0.f, 0.f};
    f32x4 o[2];
    o[0] = (f32x4){0.f, 0.f, 0.f, 0.f};
    o[1] = (f32x4){0.f, 0.f, 0.f, 0.f};

    int t0 = 0, t1 = SS / 64 - 1;
    const bool masked = (win < SS);
    if (masked) {
        t0 = (i0 - win) >> 6;        if (t0 < 0) t0 = 0;
        t1 = (i0 + 63 + win) >> 6;   if (t1 > SS / 64 - 1) t1 = SS / 64 - 1;
    }
    const int per = (t1 - t0 + nseg) / nseg;
    const int s0 = t0 + seg * per;
    const int s1 = (s0 + per - 1 < t1) ? (s0 + per - 1) : t1;
    const float scl = 0.17677669529663688f;  // 1/sqrt(32)
    const float M0 = 32.0f;                   // fixed softmax shift

    short8 kreg = *(const short8*)(Kg + (size_t)(s0 * 64 + sr) * D3 + sc8);
    short8 vreg = *(const short8*)(Vg + (size_t)vd * SS + s0 * 64 + vs8);

    for (int kt = s0; kt <= s1; kt++) {
        const int k0 = kt * 64;
        __syncthreads();
        *(short8*)&Ks[sr * 40 + sc8] = kreg;
        *(short8*)&Vt[vd * 72 + vs8] = vreg;
        __syncthreads();
        if (kt < s1) {
            kreg = *(const short8*)(Kg + (size_t)(k0 + 64 + sr) * D3 + sc8);
            vreg = *(const short8*)(Vg + (size_t)vd * SS + k0 + 64 + vs8);
        }

        f32x4 s[4];
        #pragma unroll
        for (int cb = 0; cb < 4; cb++) {
            short8 kf = *(const short8*)&Ks[(16 * cb + lm) * 40 + quad * 8];
            f32x4 a = (f32x4){0.f, 0.f, 0.f, 0.f};
            a = __builtin_amdgcn_mfma_f32_16x16x32_bf16(qh, kf, a, 0, 0, 0);
            s[cb] = a;
        }

        #pragma unroll
        for (int r = 0; r < 4; r++) {
            float p[4];
            #pragma unroll
            for (int cb = 0; cb < 4; cb++) {
                float v = s[cb][r] * scl;
                if (masked) {
                    int di = (i0 + 16 * wave + quad * 4 + r) - (k0 + 16 * cb + lm);
                    if (di > win || di < -win) v = -1e30f;
                }
                p[cb] = __expf(v - M0);
            }
            l[r] += p[0] + p[1] + p[2] + p[3];
            const int pr = (16 * wave + quad * 4 + r) * 72 + lm;
            Ps[pr +  0] = f2bfu(p[0]);
            Ps[pr + 16] = f2bfu(p[1]);
            Ps[pr + 32] = f2bfu(p[2]);
            Ps[pr + 48] = f2bfu(p[3]);
        }
        // Ps region is wave-private — no barrier needed

        #pragma unroll
        for (int kc = 0; kc < 2; kc++) {
            short8 pf = *(const short8*)&Ps[(16 * wave + lm) * 72 + 32 * kc + quad * 8];
            #pragma unroll
            for (int nh = 0; nh < 2; nh++) {
                short8 vf = *(const short8*)&Vt[(16 * nh + lm) * 72 + 32 * kc + quad * 8];
                o[nh] = __builtin_amdgcn_mfma_f32_16x16x32_bf16(pf, vf, o[nh], 0, 0, 0);
            }
        }
    }

    #pragma unroll
    for (int r = 0; r < 4; r++) {
        l[r] += __shfl_xor(l[r], 1, 64);
        l[r] += __shfl_xor(l[r], 2, 64);
        l[r] += __shfl_xor(l[r], 4, 64);
        l[r] += __shfl_xor(l[r], 8, 64);
    }

    if (nseg == 1) {
        #pragma unroll
        for (int r = 0; r < 4; r++) {
            float invl = 1.0f / l[r];
            size_t base = ((size_t)(b * SS) + i0 + 16 * wave + quad * 4 + r) * DD + h * HD + lm;
            outb[base]      = f2bfu(o[0][r] * invl);
            outb[base + 16] = f2bfu(o[1][r] * invl);
        }
    } else {
        #pragma unroll
        for (int r = 0; r < 4; r++) {
            int row = i0 + 16 * wave + quad * 4 + r;
            size_t base = ((size_t)seg * NTOK + b * SS + row) * DD + h * HD + lm;
            Of[base]      = o[0][r];
            Of[base + 16] = o[1][r];
            if (lm == 0)
                Ml[((size_t)seg * NTOK + b * SS + row) * HH + h] =
                    make_float2(M0, l[r]);
        }
    }
}

// ---------------------------------------------------------------------------
extern "C" void kernel_launch(void* const* d_in, const int* in_sizes, int n_in,
                              void* d_out, int out_size, void* d_ws, size_t ws_size,
                              hipStream_t stream)
{
    const float* xin   = (const float*)d_in[0];
    const float* scale = (const float*)d_in[1];
    const float* Win_a = (const float*)d_in[2];
    const float* bin_a = (const float*)d_in[3];
    const float* Wout_a= (const float*)d_in[4];
    const float* bout_a= (const float*)d_in[5];
    const float* Win_e = (const float*)d_in[6];
    const float* bin_e = (const float*)d_in[7];
    const float* Wout_e= (const float*)d_in[8];
    const float* bout_e= (const float*)d_in[9];
    const float* ln1_g = (const float*)d_in[10];
    const float* ln1_b = (const float*)d_in[11];
    const float* ln2_g = (const float*)d_in[12];
    const float* ln2_b = (const float*)d_in[13];
    const float* W1    = (const float*)d_in[14];
    const float* b1    = (const float*)d_in[15];
    const float* W2    = (const float*)d_in[16];
    const float* b2    = (const float*)d_in[17];
    const float* lnf_g = (const float*)d_in[18];
    const float* lnf_b = (const float*)d_in[19];

    char* ws = (char*)d_ws;
    float* X    = (float*)ws;                     ws += (size_t)NTOK * DD * 4;
    float* X2   = (float*)ws;                     ws += (size_t)NTOK * DD * 4;
    unsigned short* Xb   = (unsigned short*)ws;   ws += (size_t)NTOK * DD * 2;
    unsigned short* Xlb  = (unsigned short*)ws;   ws += (size_t)NTOK * DD * 2;
    unsigned short* X2b  = (unsigned short*)ws;   ws += (size_t)NTOK * DD * 2;
    unsigned short* ATb  = (unsigned short*)ws;   ws += (size_t)NTOK * DD * 2;
    unsigned short* QKVb = (unsigned short*)ws;   ws += (size_t)NTOK * D3 * 2;
    unsigned short* QKVl = (unsigned short*)ws;   ws += (size_t)NTOK * D3 * 2;
    unsigned short* VTh  = (unsigned short*)ws;   ws += (size_t)NTOK * DD * 2;
    unsigned short* HMLb = (unsigned short*)ws;   ws += (size_t)NTOK * MLP * 2;
    unsigned short* Wb   = (unsigned short*)ws;   ws += (size_t)W_TOT * 2;
    unsigned short* Wl0  = (unsigned short*)ws;   ws += (size_t)WL0 * 2;
    float2* Ml           = (float2*)ws;           ws += (size_t)NSEG * NTOK * HH * 8;
    float* Of            = (float*)ws;            ws += (size_t)NSEG * NTOK * DD * 4;

    unsigned short* WinA_b  = Wb + 0;
    unsigned short* WoutA_b = Wb + 393216;
    unsigned short* WinE_b  = Wb + 524288;
    unsigned short* WoutE_b = Wb + 917504;
    unsigned short* W1_b    = Wb + 1048576;
    unsigned short* W2_b    = Wb + 1572864;

    prep_kernel<<<WBLK + PBLK, 256, 0, stream>>>(
        Win_a, Wout_a, Win_e, Wout_e, W1, W2, Wb, Wl0,
        xin, scale, X, Xb, Xlb);

    float* cur = X;            float* oth = X2;
    unsigned short* curb = Xb; unsigned short* othb = X2b;

    for (int l = 0; l < 2; l++) {
        // --- full self-attention (split-K NSEG, combine+LN fused into Wout)
        if (l == 0) {
            gemm_mfma_split<<<dim3(D3 / 128, NTOK / 64), 256, 0, stream>>>(
                Xb, Xlb, WinA_b, Wl0, bin_a, QKVb, QKVl, VTh, NTOK, D3, DD);
            attn_split<<<dim3(SS / 64, HH, BB * NSEG), 256, 0, stream>>>(
                QKVb, QKVl, VTh, Of, Ml);
        } else {
            gemm_mfma<<<dim3(D3 / 128, NTOK / 64), 256, 0, stream>>>(
                curb, WinA_b + (size_t)l * D3 * DD, bin_a + (size_t)l * D3,
                nullptr, nullptr, QKVb, VTh, NTOK, D3, DD, 0);
            attn_fixed<<<dim3(SS / 64, HH, BB * NSEG), 256, 0, stream>>>(
                QKVb, VTh, nullptr, Of, Ml, 1 << 28, NSEG);
        }
        gemm_ln<true, true><<<NTOK / 16, 256, 0, stream>>>(
            nullptr, Of, Ml, WoutA_b + (size_t)l * DD * DD,
            bout_a + (size_t)l * DD, cur,
            ln1_g + l * DD, ln1_b + l * DD, oth, othb, DD);

        // --- banded self-attention (|i-j| <= 64), LN fused into Wout
        gemm_mfma<<<dim3(D3 / 128, NTOK / 64), 256, 0, stream>>>(
            othb, WinE_b + (size_t)l * D3 * DD, bin_e + (size_t)l * D3,
            nullptr, nullptr, QKVb, VTh, NTOK, D3, DD, 0);
        attn_fixed<<<dim3(SS / 64, HH, BB), 256, 0, stream>>>(
            QKVb, VTh, ATb, nullptr, nullptr, 64, 1);
        gemm_ln<false, true><<<NTOK / 16, 256, 0, stream>>>(
            ATb, nullptr, nullptr, WoutE_b + (size_t)l * DD * DD,
            bout_e + (size_t)l * DD, oth,
            ln2_g + l * DD, ln2_b + l * DD, cur, curb, DD);
        // attended now in cur/curb

        // --- MLP with exact gelu; layer-1's W2 fuses the final LayerNorm
        gemm_mfma<<<dim3(MLP / 128, NTOK / 64), 256, 0, stream>>>(
            curb, W1_b + (size_t)l * MLP * DD, b1 + (size_t)l * MLP,
            nullptr, nullptr, HMLb, nullptr, NTOK, MLP, DD, 1);
        if (l == 0) {
            // full-row no-LN GEMM: grid 256 (full machine) vs 128 before
            gemm_ln<false, false><<<NTOK / 16, 256, 0, stream>>>(
                HMLb, nullptr, nullptr, W2_b + (size_t)l * DD * MLP,
                b2 + (size_t)l * DD, cur,
                nullptr, nullptr, oth, othb, MLP);
            float* tf = cur; cur = oth; oth = tf;
            unsigned short* tb = curb; curb = othb; othb = tb;
        } else {
            gemm_ln<false, true><<<NTOK / 16, 256, 0, stream>>>(
                HMLb, nullptr, nullptr, W2_b + (size_t)l * DD * MLP,
                b2 + (size_t)l * DD, cur,
                lnf_g, lnf_b, (float*)d_out, nullptr, MLP);
        }
    }
}